// Round 4
// baseline (416.621 us; speedup 1.0000x reference)
//
#include <hip/hip_runtime.h>
#include <hip/hip_bf16.h>
#include <stdint.h>

#define C_DIM 256
#define N_DIM 4096
#define B_DIM 4

typedef __attribute__((ext_vector_type(8))) short s16x8;   // 8 bf16
typedef __attribute__((ext_vector_type(4))) short s16x4;   // 4 bf16
typedef __attribute__((ext_vector_type(4))) float f32x4;
typedef __attribute__((ext_vector_type(16))) float f32x16;

static __device__ __forceinline__ short f2bs(float f) {
    __bf16 h = (__bf16)f;                 // RNE f32->bf16
    return __builtin_bit_cast(short, h);
}
static __device__ __forceinline__ float bs2f(short s) {
    unsigned int u = ((unsigned int)(unsigned short)s) << 16;
    return __builtin_bit_cast(float, u);
}
static __device__ __forceinline__ s16x4 lo4(s16x8 v) {
    s16x4 r; r[0]=v[0]; r[1]=v[1]; r[2]=v[2]; r[3]=v[3]; return r;
}
static __device__ __forceinline__ s16x4 hi4(s16x8 v) {
    s16x4 r; r[0]=v[4]; r[1]=v[5]; r[2]=v[6]; r[3]=v[7]; return r;
}
static __device__ __forceinline__ s16x8 ld8_2x4(const short* p) {
    s16x4 a = *(const s16x4*)p;
    s16x4 b = *(const s16x4*)(p + 4);
    s16x8 r; r[0]=a[0]; r[1]=a[1]; r[2]=a[2]; r[3]=a[3];
    r[4]=b[0]; r[5]=b[1]; r[6]=b[2]; r[7]=b[3]; return r;
}

// ---------------------------------------------------------------------------
// Kernel 0: transpose+convert x,y -> xT,yT [B][N][C] bf16; convert weights.
// ---------------------------------------------------------------------------
__global__ __launch_bounds__(256)
void prep_kernel(const float* __restrict__ x, const float* __restrict__ y,
                 const float* __restrict__ wq, const float* __restrict__ wk,
                 const float* __restrict__ wv,
                 short* __restrict__ xT, short* __restrict__ yT,
                 short* __restrict__ wb)
{
    int bid = blockIdx.x;
    int t = threadIdx.x;
    if (bid < 2048) {
        const float* src = (bid < 1024) ? x : y;
        short* dst = (bid < 1024) ? xT : yT;
        int id = bid & 1023;
        int ct = id & 3;            // 4 c-tiles of 64
        int nt = (id >> 2) & 63;    // 64 n-tiles of 64
        int b  = id >> 8;           // 4 batches
        int n0 = nt * 64, c0 = ct * 64;
        __shared__ short T[64][66]; // odd dword stride -> conflict-free
        int l = t & 63;
        int wv_ = t >> 6;
        #pragma unroll
        for (int p = 0; p < 16; ++p) {
            int c = wv_ + p * 4;
            float v = src[((size_t)(b * C_DIM + c0 + c)) * N_DIM + n0 + l];
            T[l][c] = f2bs(v);
        }
        __syncthreads();
        #pragma unroll
        for (int p = 0; p < 16; ++p) {
            int n = wv_ + p * 4;
            dst[((size_t)(b * N_DIM + n0 + n)) * C_DIM + c0 + l] = T[n][l];
        }
    } else {
        // weights: 96 blocks x 2048 elems
        int id = bid - 2048;
        const float* w = (id < 32) ? wq : (id < 64) ? wk : wv;
        short* dst = wb + (size_t)(id / 32) * (C_DIM * C_DIM);
        int off = (id & 31) * 2048 + t * 8;
        f32x4 a  = *(const f32x4*)(w + off);
        f32x4 b4 = *(const f32x4*)(w + off + 4);
        s16x8 r;
        r[0]=f2bs(a[0]);  r[1]=f2bs(a[1]);  r[2]=f2bs(a[2]);  r[3]=f2bs(a[3]);
        r[4]=f2bs(b4[0]); r[5]=f2bs(b4[1]); r[6]=f2bs(b4[2]); r[7]=f2bs(b4[3]);
        *(s16x8*)(dst + off) = r;
    }
}

// ---------------------------------------------------------------------------
// Kernel 1: projections. Qb,Kb = [B][N][256]; Vb = [B][256][N].
// Q is pre-scaled by log2(e) so attention softmax can use exp2 directly.
// ---------------------------------------------------------------------------
__global__ __launch_bounds__(256)
void proj_kernel(const short* __restrict__ xT, const short* __restrict__ yT,
                 const short* __restrict__ wb,
                 short* __restrict__ Qb, short* __restrict__ Kb,
                 short* __restrict__ Vb)
{
    int bid = blockIdx.x;              // 3072 = 12 * 64 * 4
    int ot = bid & 3;
    int nt = (bid >> 2) & 63;
    int bp = bid >> 8;                 // 0..11 = b*3 + p
    int b = bp / 3, p = bp % 3;
    int n0 = nt * 64, o0 = ot * 64;
    const short* src = (p == 0) ? xT : yT;
    const short* w = wb + (size_t)p * C_DIM * C_DIM;

    __shared__ __align__(16) short Xs[64][264];

    int t = threadIdx.x;
    const short* srcb = src + (size_t)(b * N_DIM + n0) * C_DIM;
    #pragma unroll
    for (int pas = 0; pas < 8; ++pas) {
        int slot = pas * 256 + t;
        int row = slot >> 5, ck = slot & 31;
        *(s16x8*)&Xs[row][ck * 8] = *(const s16x8*)&srcb[(size_t)row * C_DIM + ck * 8];
    }
    __syncthreads();

    int lane = t & 63;
    int wid = t >> 6;
    int m = lane & 15, q = lane >> 4;
    f32x4 acc[4] = {};

    if (p < 2) {
        #pragma unroll
        for (int kk = 0; kk < 8; ++kk) {
            s16x8 af = *(const s16x8*)&Xs[wid * 16 + m][kk * 32 + q * 8];
            #pragma unroll
            for (int ob = 0; ob < 4; ++ob) {
                s16x8 bf = *(const s16x8*)&w[(size_t)(o0 + ob * 16 + m) * C_DIM + kk * 32 + q * 8];
                acc[ob] = __builtin_amdgcn_mfma_f32_16x16x32_bf16(af, bf, acc[ob], 0, 0, 0);
            }
        }
        float sc = (p == 0) ? 1.4426950408889634f : 1.0f;  // log2(e) for Q
        short* dst = ((p == 0) ? Qb : Kb) + (size_t)b * N_DIM * C_DIM;
        #pragma unroll
        for (int ob = 0; ob < 4; ++ob)
            #pragma unroll
            for (int r = 0; r < 4; ++r) {
                int n = n0 + wid * 16 + q * 4 + r;
                int o = o0 + ob * 16 + m;
                dst[(size_t)n * C_DIM + o] = f2bs(acc[ob][r] * sc);
            }
    } else {
        #pragma unroll
        for (int kk = 0; kk < 8; ++kk) {
            s16x8 af = *(const s16x8*)&w[(size_t)(o0 + wid * 16 + m) * C_DIM + kk * 32 + q * 8];
            #pragma unroll
            for (int nb = 0; nb < 4; ++nb) {
                s16x8 bf = *(const s16x8*)&Xs[nb * 16 + m][kk * 32 + q * 8];
                acc[nb] = __builtin_amdgcn_mfma_f32_16x16x32_bf16(af, bf, acc[nb], 0, 0, 0);
            }
        }
        short* dst = Vb + (size_t)b * C_DIM * N_DIM;
        #pragma unroll
        for (int nb = 0; nb < 4; ++nb)
            #pragma unroll
            for (int r = 0; r < 4; ++r) {
                int o = o0 + wid * 16 + q * 4 + r;
                int n = n0 + nb * 16 + m;
                dst[(size_t)o * N_DIM + n] = f2bs(acc[nb][r]);
            }
    }
}

// ---------------------------------------------------------------------------
// Kernel 2: flash attention, SPLIT-K over 2 key-halves -> 512 blocks,
// 2 blocks/CU co-resident (LDS 78.8 KB, VGPR ~100). R0's proven asymmetric
// 8-wave structure; single-buffered K/V/P with R1's proven 3-barrier hazard
// schedule (K: issue-A/write-B; V: issue-C/write-next-A).
// Writes UNNORMALIZED partial O (bf16) + per-q (m, s); merge_kernel combines.
//
// Waves 0-3 "QK" (ib = w>>1, jb = w&1): S^T = mfma(K rows, Q cols), 2 indep
//   8-chains; softmax partials; PV c-strip of 32. Waves 4-7: 3 c-strips each.
// ---------------------------------------------------------------------------
__global__ __launch_bounds__(512, 4)
void attn_kernel(const short* __restrict__ Qb, const short* __restrict__ Kb,
                 const short* __restrict__ Vb,
                 short* __restrict__ Op,    // [2][B][C][N] bf16, unnormalized
                 float* __restrict__ ms)    // [2][B][2][N] f32 (m, s)
{
    int bid0 = blockIdx.x;
    int bid = (bid0 & 7) * 64 + (bid0 >> 3);   // XCD swizzle: 64 blocks/XCD share (b,half)
    int it = bid & 63;
    int half = (bid >> 6) & 1;
    int b = bid >> 7;
    int i0 = it * 64;

    int t = threadIdx.x;
    int w = t >> 6;
    int lane = t & 63;
    int il = lane & 31;
    int hi = lane >> 5;

    bool isQK = (w < 4);
    int ib = isQK ? (w >> 1) : ((w - 4) >> 1);
    int jb = w & 1;                                  // QK waves only
    int cbase = isQK ? ((w & 1) * 32) : (64 + (w & 1) * 96);
    int ncb = isQK ? 1 : 3;

    __shared__ __align__(16) short Ks[64][264];    // 33,792 B
    __shared__ __align__(16) short Vs[256][68];    // 34,816 B (8B-aligned rows)
    __shared__ __align__(16) short Ps[64][72];     //  9,216 B
    __shared__ float mpart[2][64];
    __shared__ float spart[2][64];                 // total 78,848 B -> 2 blocks/CU

    const short* Qp = Qb + (size_t)b * N_DIM * C_DIM;
    const short* Kp = Kb + (size_t)b * N_DIM * C_DIM + (size_t)half * 2048 * C_DIM;
    const short* Vp = Vb + (size_t)b * C_DIM * N_DIM + half * 2048;

    // staging maps (512 threads): K tile 64x256 = 4 chunks, V tile 256x64 = 4
    int krb = t >> 5, kck = t & 31;   // K rows p*16+krb, granule kck
    int vrb = t >> 3, vck = t & 7;    // V rows p*64+vrb, granule vck

    // Q fragments: B[k=c][col=q], lane holds q = ib*32+il
    s16x8 qf[16];
    if (isQK) {
        const short* qrow = Qp + (size_t)(i0 + ib * 32 + il) * C_DIM + hi * 8;
        #pragma unroll
        for (int kk = 0; kk < 16; ++kk)
            qf[kk] = *(const s16x8*)&qrow[kk * 16];
    }

    // prologue: stage K(0), V(0)
    {
        s16x8 kr[4], vr[4];
        #pragma unroll
        for (int p = 0; p < 4; ++p)
            kr[p] = *(const s16x8*)&Kp[(size_t)(p * 16 + krb) * C_DIM + kck * 8];
        #pragma unroll
        for (int p = 0; p < 4; ++p)
            vr[p] = *(const s16x8*)&Vp[(size_t)(p * 64 + vrb) * N_DIM + vck * 8];
        #pragma unroll
        for (int p = 0; p < 4; ++p)
            *(s16x8*)&Ks[p * 16 + krb][kck * 8] = kr[p];
        #pragma unroll
        for (int p = 0; p < 4; ++p) {
            *(s16x4*)&Vs[p * 64 + vrb][vck * 8]     = lo4(vr[p]);
            *(s16x4*)&Vs[p * 64 + vrb][vck * 8 + 4] = hi4(vr[p]);
        }
    }
    __syncthreads();

    f32x16 acc[3] = {};
    float mrun = -3e38f, srun = 0.f;
    s16x8 vreg[4];   // V(jt+1): issued in phase C, written next phase A

    for (int jt = 0; jt < 32; ++jt) {
        bool pf = (jt < 31);

        // ---- Phase A: V-write (staged in prev C), issue K-next, QK MFMA ----
        if (jt > 0) {
            #pragma unroll
            for (int p = 0; p < 4; ++p) {
                *(s16x4*)&Vs[p * 64 + vrb][vck * 8]     = lo4(vreg[p]);
                *(s16x4*)&Vs[p * 64 + vrb][vck * 8 + 4] = hi4(vreg[p]);
            }
        }
        s16x8 kreg[4];
        if (pf) {
            const short* kg = Kp + (size_t)(jt + 1) * 64 * C_DIM;
            #pragma unroll
            for (int p = 0; p < 4; ++p)
                kreg[p] = *(const s16x8*)&kg[(size_t)(p * 16 + krb) * C_DIM + kck * 8];
        }
        f32x16 sv;
        if (isQK) {
            f32x16 sv0 = {}, sv1 = {};
            __builtin_amdgcn_s_setprio(1);
            #pragma unroll
            for (int kk = 0; kk < 8; ++kk) {
                s16x8 a0 = *(const s16x8*)&Ks[jb * 32 + il][kk * 16 + hi * 8];
                sv0 = __builtin_amdgcn_mfma_f32_32x32x16_bf16(a0, qf[kk], sv0, 0, 0, 0);
                s16x8 a1 = *(const s16x8*)&Ks[jb * 32 + il][(kk + 8) * 16 + hi * 8];
                sv1 = __builtin_amdgcn_mfma_f32_32x32x16_bf16(a1, qf[kk + 8], sv1, 0, 0, 0);
            }
            __builtin_amdgcn_s_setprio(0);
            #pragma unroll
            for (int r = 0; r < 16; ++r) sv[r] = sv0[r] + sv1[r];
            float tmax = sv[0];
            #pragma unroll
            for (int r = 1; r < 16; ++r) tmax = fmaxf(tmax, sv[r]);
            tmax = fmaxf(tmax, __shfl_xor(tmax, 32, 64));
            if (hi == 0) mpart[jb][ib * 32 + il] = tmax;
        }
        __syncthreads();   // bar1: mpart ready; Ks(jt) reads + Vs(jt) writes done

        // ---- Phase B: K-write, softmax, P write ----------------------------
        if (pf) {
            #pragma unroll
            for (int p = 0; p < 4; ++p)
                *(s16x8*)&Ks[p * 16 + krb][kck * 8] = kreg[p];
        }
        float mnew = fmaxf(mrun, fmaxf(mpart[0][ib * 32 + il], mpart[1][ib * 32 + il]));
        float alpha = exp2f(mrun - mnew);
        mrun = mnew;
        if (isQK) {
            float ts = 0.f;
            #pragma unroll
            for (int r = 0; r < 16; ++r) {
                float pe = exp2f(sv[r] - mnew);   // Q pre-scaled by log2(e)
                sv[r] = pe;
                ts += pe;
            }
            ts += __shfl_xor(ts, 32, 64);
            if (hi == 0) spart[jb][ib * 32 + il] = ts;
            // P rows j = jb*32 + 8g + 4hi + (0..3), col q = il -> Ps[q][j]
            #pragma unroll
            for (int g = 0; g < 4; ++g) {
                s16x4 pv;
                pv[0] = f2bs(sv[4 * g + 0]); pv[1] = f2bs(sv[4 * g + 1]);
                pv[2] = f2bs(sv[4 * g + 2]); pv[3] = f2bs(sv[4 * g + 3]);
                *(s16x4*)&Ps[ib * 32 + il][jb * 32 + g * 8 + hi * 4] = pv;
            }
        }
        if (__any(alpha != 1.f)) {          // T13: skip rescale if max unchanged
            #pragma unroll
            for (int cb = 0; cb < 3; ++cb)
                if (cb < ncb) {
                    #pragma unroll
                    for (int r = 0; r < 16; ++r) acc[cb][r] *= alpha;
                }
        }
        __syncthreads();   // bar2: Ps + spart + Ks(jt+1) staged

        // ---- Phase C: PV; issue V-next -------------------------------------
        srun = srun * alpha + spart[0][ib * 32 + il] + spart[1][ib * 32 + il];
        if (pf) {
            const short* vg = Vp + (size_t)(jt + 1) * 64;
            #pragma unroll
            for (int p = 0; p < 4; ++p)
                vreg[p] = *(const s16x8*)&vg[(size_t)(p * 64 + vrb) * N_DIM + vck * 8];
        }
        __builtin_amdgcn_s_setprio(1);
        #pragma unroll
        for (int kc = 0; kc < 4; ++kc) {
            s16x8 bf = *(const s16x8*)&Ps[ib * 32 + il][kc * 16 + hi * 8];
            #pragma unroll
            for (int cb = 0; cb < 3; ++cb)
                if (cb < ncb) {
                    s16x8 af = ld8_2x4(&Vs[cbase + cb * 32 + il][kc * 16 + hi * 8]);
                    acc[cb] = __builtin_amdgcn_mfma_f32_32x32x16_bf16(af, bf, acc[cb], 0, 0, 0);
                }
        }
        __builtin_amdgcn_s_setprio(0);
        __syncthreads();   // bar3: Vs + Ps reads done before next A/B writes
    }

    // epilogue: unnormalized partial O (bf16) + (m, s)
    int i = i0 + ib * 32 + il;
    short* opb = Op + (((size_t)half * B_DIM + b) * C_DIM) * N_DIM;
    #pragma unroll
    for (int cb = 0; cb < 3; ++cb)
        if (cb < ncb) {
            #pragma unroll
            for (int r = 0; r < 16; ++r) {
                int c = cbase + cb * 32 + (r & 3) + 8 * (r >> 2) + 4 * hi;
                opb[(size_t)c * N_DIM + i] = f2bs(acc[cb][r]);
            }
        }
    if ((w == 0 || w == 2) && hi == 0) {
        size_t mb = (((size_t)half * B_DIM + b) * 2) * N_DIM;
        ms[mb + i] = mrun;
        ms[mb + N_DIM + i] = srun;
    }
}

// ---------------------------------------------------------------------------
// Kernel 3: flash-merge of the two key-halves + gamma/residual epilogue.
// out = g * (O0*w0 + O1*w1) / (s0*w0 + s1*w1) + x,  w_h = 2^(m_h - max)
// ---------------------------------------------------------------------------
__global__ __launch_bounds__(256)
void merge_kernel(const short* __restrict__ Op, const float* __restrict__ ms,
                  const float* __restrict__ x, const float* __restrict__ gamma,
                  float* __restrict__ out)
{
    size_t base = ((size_t)blockIdx.x * 256 + threadIdx.x) * 8;
    int n = (int)(base & (N_DIM - 1));
    int b = (int)(base >> 20);                     // 256*4096 = 2^20 per batch
    const size_t HSZ = (size_t)B_DIM * C_DIM * N_DIM;

    s16x8 o0 = *(const s16x8*)&Op[base];
    s16x8 o1 = *(const s16x8*)&Op[HSZ + base];

    size_t m0o = ((size_t)b * 2) * N_DIM + n;
    size_t m1o = (((size_t)B_DIM + b) * 2) * N_DIM + n;
    f32x4 m0a = *(const f32x4*)&ms[m0o];
    f32x4 m0b = *(const f32x4*)&ms[m0o + 4];
    f32x4 s0a = *(const f32x4*)&ms[m0o + N_DIM];
    f32x4 s0b = *(const f32x4*)&ms[m0o + N_DIM + 4];
    f32x4 m1a = *(const f32x4*)&ms[m1o];
    f32x4 m1b = *(const f32x4*)&ms[m1o + 4];
    f32x4 s1a = *(const f32x4*)&ms[m1o + N_DIM];
    f32x4 s1b = *(const f32x4*)&ms[m1o + N_DIM + 4];

    f32x4 xa = *(const f32x4*)&x[base];
    f32x4 xb = *(const f32x4*)&x[base + 4];
    float g = gamma[0];

    f32x4 ra, rb;
    #pragma unroll
    for (int e = 0; e < 4; ++e) {
        float m = fmaxf(m0a[e], m1a[e]);
        float w0 = exp2f(m0a[e] - m), w1 = exp2f(m1a[e] - m);
        float den = s0a[e] * w0 + s1a[e] * w1;
        float o = (bs2f(o0[e]) * w0 + bs2f(o1[e]) * w1) / den;
        ra[e] = g * o + xa[e];
    }
    #pragma unroll
    for (int e = 0; e < 4; ++e) {
        float m = fmaxf(m0b[e], m1b[e]);
        float w0 = exp2f(m0b[e] - m), w1 = exp2f(m1b[e] - m);
        float den = s0b[e] * w0 + s1b[e] * w1;
        float o = (bs2f(o0[e + 4]) * w0 + bs2f(o1[e + 4]) * w1) / den;
        rb[e] = g * o + xb[e];
    }
    *(f32x4*)&out[base] = ra;
    *(f32x4*)&out[base + 4] = rb;
}

// ---------------------------------------------------------------------------
extern "C" void kernel_launch(void* const* d_in, const int* in_sizes, int n_in,
                              void* d_out, int out_size, void* d_ws, size_t ws_size,
                              hipStream_t stream) {
    const float* x  = (const float*)d_in[0];
    const float* y  = (const float*)d_in[1];
    const float* wq = (const float*)d_in[2];
    const float* wk = (const float*)d_in[3];
    const float* wv = (const float*)d_in[4];
    const float* gm = (const float*)d_in[5];
    float* out = (float*)d_out;

    char* ws = (char*)d_ws;
    const size_t SZ = (size_t)B_DIM * N_DIM * C_DIM * sizeof(short); // 8 MB
    short* xT = (short*)(ws);
    short* yT = (short*)(ws + SZ);
    short* Qb = (short*)(ws + 2 * SZ);
    short* Kb = (short*)(ws + 3 * SZ);
    short* Vb = (short*)(ws + 4 * SZ);
    short* wb = (short*)(ws + 5 * SZ); // 384 KB, dead after proj
    // overlays (dead after proj_kernel):
    short* Op = xT;                    // [2][B][C][N] bf16 = 16 MB (xT+yT)
    float* ms = (float*)wb;            // [2][B][2][N] f32 = 256 KB

    prep_kernel<<<dim3(2048 + 96), dim3(256), 0, stream>>>(x, y, wq, wk, wv, xT, yT, wb);
    proj_kernel<<<dim3(3072), dim3(256), 0, stream>>>(xT, yT, wb, Qb, Kb, Vb);
    attn_kernel<<<dim3(512), dim3(512), 0, stream>>>(Qb, Kb, Vb, Op, ms);
    merge_kernel<<<dim3(2048), dim3(256), 0, stream>>>(Op, ms, x, gm, out);
}

// Round 5
// 205.275 us; speedup vs baseline: 2.0296x; 2.0296x over previous
//
#include <hip/hip_runtime.h>
#include <hip/hip_bf16.h>
#include <stdint.h>

#define C_DIM 256
#define N_DIM 4096
#define B_DIM 4

typedef __attribute__((ext_vector_type(8))) short s16x8;   // 8 bf16
typedef __attribute__((ext_vector_type(4))) short s16x4;   // 4 bf16
typedef __attribute__((ext_vector_type(4))) float f32x4;
typedef __attribute__((ext_vector_type(16))) float f32x16;

static __device__ __forceinline__ short f2bs(float f) {
    __bf16 h = (__bf16)f;                 // RNE f32->bf16
    return __builtin_bit_cast(short, h);
}
static __device__ __forceinline__ float bs2f(short s) {
    unsigned int u = ((unsigned int)(unsigned short)s) << 16;
    return __builtin_bit_cast(float, u);
}
static __device__ __forceinline__ s16x4 lo4(s16x8 v) {
    s16x4 r; r[0]=v[0]; r[1]=v[1]; r[2]=v[2]; r[3]=v[3]; return r;
}
static __device__ __forceinline__ s16x4 hi4(s16x8 v) {
    s16x4 r; r[0]=v[4]; r[1]=v[5]; r[2]=v[6]; r[3]=v[7]; return r;
}
static __device__ __forceinline__ s16x8 ld8_2x4(const short* p) {
    s16x4 a = *(const s16x4*)p;
    s16x4 b = *(const s16x4*)(p + 4);
    s16x8 r; r[0]=a[0]; r[1]=a[1]; r[2]=a[2]; r[3]=a[3];
    r[4]=b[0]; r[5]=b[1]; r[6]=b[2]; r[7]=b[3]; return r;
}

// ---------------------------------------------------------------------------
// Kernel 0: transpose+convert x,y -> xT,yT [B][N][C] bf16; convert weights.
// ---------------------------------------------------------------------------
__global__ __launch_bounds__(256)
void prep_kernel(const float* __restrict__ x, const float* __restrict__ y,
                 const float* __restrict__ wq, const float* __restrict__ wk,
                 const float* __restrict__ wv,
                 short* __restrict__ xT, short* __restrict__ yT,
                 short* __restrict__ wb)
{
    int bid = blockIdx.x;
    int t = threadIdx.x;
    if (bid < 2048) {
        const float* src = (bid < 1024) ? x : y;
        short* dst = (bid < 1024) ? xT : yT;
        int id = bid & 1023;
        int ct = id & 3;            // 4 c-tiles of 64
        int nt = (id >> 2) & 63;    // 64 n-tiles of 64
        int b  = id >> 8;           // 4 batches
        int n0 = nt * 64, c0 = ct * 64;
        __shared__ short T[64][66]; // odd dword stride -> conflict-free
        int l = t & 63;
        int wv_ = t >> 6;
        #pragma unroll
        for (int p = 0; p < 16; ++p) {
            int c = wv_ + p * 4;
            float v = src[((size_t)(b * C_DIM + c0 + c)) * N_DIM + n0 + l];
            T[l][c] = f2bs(v);
        }
        __syncthreads();
        #pragma unroll
        for (int p = 0; p < 16; ++p) {
            int n = wv_ + p * 4;
            dst[((size_t)(b * N_DIM + n0 + n)) * C_DIM + c0 + l] = T[n][l];
        }
    } else {
        // weights: 96 blocks x 2048 elems
        int id = bid - 2048;
        const float* w = (id < 32) ? wq : (id < 64) ? wk : wv;
        short* dst = wb + (size_t)(id / 32) * (C_DIM * C_DIM);
        int off = (id & 31) * 2048 + t * 8;
        f32x4 a  = *(const f32x4*)(w + off);
        f32x4 b4 = *(const f32x4*)(w + off + 4);
        s16x8 r;
        r[0]=f2bs(a[0]);  r[1]=f2bs(a[1]);  r[2]=f2bs(a[2]);  r[3]=f2bs(a[3]);
        r[4]=f2bs(b4[0]); r[5]=f2bs(b4[1]); r[6]=f2bs(b4[2]); r[7]=f2bs(b4[3]);
        *(s16x8*)(dst + off) = r;
    }
}

// ---------------------------------------------------------------------------
// Kernel 1: projections. Qb,Kb = [B][N][256]; Vb = [B][256][N].
// Q is pre-scaled by log2(e) so attention softmax can use exp2 directly.
// ---------------------------------------------------------------------------
__global__ __launch_bounds__(256)
void proj_kernel(const short* __restrict__ xT, const short* __restrict__ yT,
                 const short* __restrict__ wb,
                 short* __restrict__ Qb, short* __restrict__ Kb,
                 short* __restrict__ Vb)
{
    int bid = blockIdx.x;              // 3072 = 12 * 64 * 4
    int ot = bid & 3;
    int nt = (bid >> 2) & 63;
    int bp = bid >> 8;                 // 0..11 = b*3 + p
    int b = bp / 3, p = bp % 3;
    int n0 = nt * 64, o0 = ot * 64;
    const short* src = (p == 0) ? xT : yT;
    const short* w = wb + (size_t)p * C_DIM * C_DIM;

    __shared__ __align__(16) short Xs[64][264];

    int t = threadIdx.x;
    const short* srcb = src + (size_t)(b * N_DIM + n0) * C_DIM;
    #pragma unroll
    for (int pas = 0; pas < 8; ++pas) {
        int slot = pas * 256 + t;
        int row = slot >> 5, ck = slot & 31;
        *(s16x8*)&Xs[row][ck * 8] = *(const s16x8*)&srcb[(size_t)row * C_DIM + ck * 8];
    }
    __syncthreads();

    int lane = t & 63;
    int wid = t >> 6;
    int m = lane & 15, q = lane >> 4;
    f32x4 acc[4] = {};

    if (p < 2) {
        #pragma unroll
        for (int kk = 0; kk < 8; ++kk) {
            s16x8 af = *(const s16x8*)&Xs[wid * 16 + m][kk * 32 + q * 8];
            #pragma unroll
            for (int ob = 0; ob < 4; ++ob) {
                s16x8 bf = *(const s16x8*)&w[(size_t)(o0 + ob * 16 + m) * C_DIM + kk * 32 + q * 8];
                acc[ob] = __builtin_amdgcn_mfma_f32_16x16x32_bf16(af, bf, acc[ob], 0, 0, 0);
            }
        }
        float sc = (p == 0) ? 1.4426950408889634f : 1.0f;  // log2(e) for Q
        short* dst = ((p == 0) ? Qb : Kb) + (size_t)b * N_DIM * C_DIM;
        #pragma unroll
        for (int ob = 0; ob < 4; ++ob)
            #pragma unroll
            for (int r = 0; r < 4; ++r) {
                int n = n0 + wid * 16 + q * 4 + r;
                int o = o0 + ob * 16 + m;
                dst[(size_t)n * C_DIM + o] = f2bs(acc[ob][r] * sc);
            }
    } else {
        #pragma unroll
        for (int kk = 0; kk < 8; ++kk) {
            s16x8 af = *(const s16x8*)&w[(size_t)(o0 + wid * 16 + m) * C_DIM + kk * 32 + q * 8];
            #pragma unroll
            for (int nb = 0; nb < 4; ++nb) {
                s16x8 bf = *(const s16x8*)&Xs[nb * 16 + m][kk * 32 + q * 8];
                acc[nb] = __builtin_amdgcn_mfma_f32_16x16x32_bf16(af, bf, acc[nb], 0, 0, 0);
            }
        }
        short* dst = Vb + (size_t)b * C_DIM * N_DIM;
        #pragma unroll
        for (int nb = 0; nb < 4; ++nb)
            #pragma unroll
            for (int r = 0; r < 4; ++r) {
                int o = o0 + wid * 16 + q * 4 + r;
                int n = n0 + nb * 16 + m;
                dst[(size_t)o * N_DIM + n] = f2bs(acc[nb][r]);
            }
    }
}

// ---------------------------------------------------------------------------
// Kernel 2: flash attention, SPLIT-K over 2 key-halves -> 512 blocks,
// 2 blocks/CU co-resident via LDS (78.8 KB). launch_bounds(512,2): VGPR cap
// 128 (structure needs ~100; R4's (512,4) forced 64 -> catastrophic spill).
// R0's asymmetric 8-wave structure; single-buffered K/V/P, 3-barrier hazard
// schedule (K: issue-A/write-B; V: issue-C/write-next-A).
// Writes UNNORMALIZED partial O (bf16) + per-q (m, s); merge_kernel combines.
// ---------------------------------------------------------------------------
__global__ __launch_bounds__(512, 2)
void attn_kernel(const short* __restrict__ Qb, const short* __restrict__ Kb,
                 const short* __restrict__ Vb,
                 short* __restrict__ Op,    // [2][B][C][N] bf16, unnormalized
                 float* __restrict__ ms)    // [2][B][2][N] f32 (m, s)
{
    int bid0 = blockIdx.x;
    int bid = (bid0 & 7) * 64 + (bid0 >> 3);   // XCD swizzle: 64 blocks/XCD share (b,half)
    int it = bid & 63;
    int half = (bid >> 6) & 1;
    int b = bid >> 7;
    int i0 = it * 64;

    int t = threadIdx.x;
    int w = t >> 6;
    int lane = t & 63;
    int il = lane & 31;
    int hi = lane >> 5;

    bool isQK = (w < 4);
    int ib = isQK ? (w >> 1) : ((w - 4) >> 1);
    int jb = w & 1;                                  // QK waves only
    int cbase = isQK ? ((w & 1) * 32) : (64 + (w & 1) * 96);
    int ncb = isQK ? 1 : 3;

    __shared__ __align__(16) short Ks[64][264];    // 33,792 B
    __shared__ __align__(16) short Vs[256][68];    // 34,816 B (8B-aligned rows)
    __shared__ __align__(16) short Ps[64][72];     //  9,216 B
    __shared__ float mpart[2][64];
    __shared__ float spart[2][64];                 // total 78,848 B -> 2 blocks/CU

    const short* Qp = Qb + (size_t)b * N_DIM * C_DIM;
    const short* Kp = Kb + (size_t)b * N_DIM * C_DIM + (size_t)half * 2048 * C_DIM;
    const short* Vp = Vb + (size_t)b * C_DIM * N_DIM + half * 2048;

    // staging maps (512 threads): K tile 64x256 = 4 chunks, V tile 256x64 = 4
    int krb = t >> 5, kck = t & 31;   // K rows p*16+krb, granule kck
    int vrb = t >> 3, vck = t & 7;    // V rows p*64+vrb, granule vck

    // Q fragments: B[k=c][col=q], lane holds q = ib*32+il
    s16x8 qf[16];
    if (isQK) {
        const short* qrow = Qp + (size_t)(i0 + ib * 32 + il) * C_DIM + hi * 8;
        #pragma unroll
        for (int kk = 0; kk < 16; ++kk)
            qf[kk] = *(const s16x8*)&qrow[kk * 16];
    }

    // prologue: stage K(0), V(0)
    {
        s16x8 kr[4], vr[4];
        #pragma unroll
        for (int p = 0; p < 4; ++p)
            kr[p] = *(const s16x8*)&Kp[(size_t)(p * 16 + krb) * C_DIM + kck * 8];
        #pragma unroll
        for (int p = 0; p < 4; ++p)
            vr[p] = *(const s16x8*)&Vp[(size_t)(p * 64 + vrb) * N_DIM + vck * 8];
        #pragma unroll
        for (int p = 0; p < 4; ++p)
            *(s16x8*)&Ks[p * 16 + krb][kck * 8] = kr[p];
        #pragma unroll
        for (int p = 0; p < 4; ++p) {
            *(s16x4*)&Vs[p * 64 + vrb][vck * 8]     = lo4(vr[p]);
            *(s16x4*)&Vs[p * 64 + vrb][vck * 8 + 4] = hi4(vr[p]);
        }
    }
    __syncthreads();

    f32x16 acc[3] = {};
    float mrun = -3e38f, srun = 0.f;
    s16x8 vreg[4];   // V(jt+1): issued in phase C, written next phase A

    for (int jt = 0; jt < 32; ++jt) {
        bool pf = (jt < 31);

        // ---- Phase A: V-write (staged in prev C), issue K-next, QK MFMA ----
        if (jt > 0) {
            #pragma unroll
            for (int p = 0; p < 4; ++p) {
                *(s16x4*)&Vs[p * 64 + vrb][vck * 8]     = lo4(vreg[p]);
                *(s16x4*)&Vs[p * 64 + vrb][vck * 8 + 4] = hi4(vreg[p]);
            }
        }
        s16x8 kreg[4];
        if (pf) {
            const short* kg = Kp + (size_t)(jt + 1) * 64 * C_DIM;
            #pragma unroll
            for (int p = 0; p < 4; ++p)
                kreg[p] = *(const s16x8*)&kg[(size_t)(p * 16 + krb) * C_DIM + kck * 8];
        }
        f32x16 sv;
        if (isQK) {
            f32x16 sv0 = {}, sv1 = {};
            __builtin_amdgcn_s_setprio(1);
            #pragma unroll
            for (int kk = 0; kk < 8; ++kk) {
                s16x8 a0 = *(const s16x8*)&Ks[jb * 32 + il][kk * 16 + hi * 8];
                sv0 = __builtin_amdgcn_mfma_f32_32x32x16_bf16(a0, qf[kk], sv0, 0, 0, 0);
                s16x8 a1 = *(const s16x8*)&Ks[jb * 32 + il][(kk + 8) * 16 + hi * 8];
                sv1 = __builtin_amdgcn_mfma_f32_32x32x16_bf16(a1, qf[kk + 8], sv1, 0, 0, 0);
            }
            __builtin_amdgcn_s_setprio(0);
            #pragma unroll
            for (int r = 0; r < 16; ++r) sv[r] = sv0[r] + sv1[r];
            float tmax = sv[0];
            #pragma unroll
            for (int r = 1; r < 16; ++r) tmax = fmaxf(tmax, sv[r]);
            tmax = fmaxf(tmax, __shfl_xor(tmax, 32, 64));
            if (hi == 0) mpart[jb][ib * 32 + il] = tmax;
        }
        __syncthreads();   // bar1: mpart ready; Ks(jt) reads + Vs(jt) writes done

        // ---- Phase B: K-write, softmax, P write ----------------------------
        if (pf) {
            #pragma unroll
            for (int p = 0; p < 4; ++p)
                *(s16x8*)&Ks[p * 16 + krb][kck * 8] = kreg[p];
        }
        float mnew = fmaxf(mrun, fmaxf(mpart[0][ib * 32 + il], mpart[1][ib * 32 + il]));
        float alpha = exp2f(mrun - mnew);
        mrun = mnew;
        if (isQK) {
            float ts = 0.f;
            #pragma unroll
            for (int r = 0; r < 16; ++r) {
                float pe = exp2f(sv[r] - mnew);   // Q pre-scaled by log2(e)
                sv[r] = pe;
                ts += pe;
            }
            ts += __shfl_xor(ts, 32, 64);
            if (hi == 0) spart[jb][ib * 32 + il] = ts;
            // P rows j = jb*32 + 8g + 4hi + (0..3), col q = il -> Ps[q][j]
            #pragma unroll
            for (int g = 0; g < 4; ++g) {
                s16x4 pv;
                pv[0] = f2bs(sv[4 * g + 0]); pv[1] = f2bs(sv[4 * g + 1]);
                pv[2] = f2bs(sv[4 * g + 2]); pv[3] = f2bs(sv[4 * g + 3]);
                *(s16x4*)&Ps[ib * 32 + il][jb * 32 + g * 8 + hi * 4] = pv;
            }
        }
        if (__any(alpha != 1.f)) {          // T13: skip rescale if max unchanged
            #pragma unroll
            for (int cb = 0; cb < 3; ++cb)
                if (cb < ncb) {
                    #pragma unroll
                    for (int r = 0; r < 16; ++r) acc[cb][r] *= alpha;
                }
        }
        __syncthreads();   // bar2: Ps + spart + Ks(jt+1) staged

        // ---- Phase C: PV; issue V-next -------------------------------------
        srun = srun * alpha + spart[0][ib * 32 + il] + spart[1][ib * 32 + il];
        if (pf) {
            const short* vg = Vp + (size_t)(jt + 1) * 64;
            #pragma unroll
            for (int p = 0; p < 4; ++p)
                vreg[p] = *(const s16x8*)&vg[(size_t)(p * 64 + vrb) * N_DIM + vck * 8];
        }
        __builtin_amdgcn_s_setprio(1);
        #pragma unroll
        for (int kc = 0; kc < 4; ++kc) {
            s16x8 bf = *(const s16x8*)&Ps[ib * 32 + il][kc * 16 + hi * 8];
            #pragma unroll
            for (int cb = 0; cb < 3; ++cb)
                if (cb < ncb) {
                    s16x8 af = ld8_2x4(&Vs[cbase + cb * 32 + il][kc * 16 + hi * 8]);
                    acc[cb] = __builtin_amdgcn_mfma_f32_32x32x16_bf16(af, bf, acc[cb], 0, 0, 0);
                }
        }
        __builtin_amdgcn_s_setprio(0);
        __syncthreads();   // bar3: Vs + Ps reads done before next A/B writes
    }

    // epilogue: unnormalized partial O (bf16) + (m, s)
    int i = i0 + ib * 32 + il;
    short* opb = Op + (((size_t)half * B_DIM + b) * C_DIM) * N_DIM;
    #pragma unroll
    for (int cb = 0; cb < 3; ++cb)
        if (cb < ncb) {
            #pragma unroll
            for (int r = 0; r < 16; ++r) {
                int c = cbase + cb * 32 + (r & 3) + 8 * (r >> 2) + 4 * hi;
                opb[(size_t)c * N_DIM + i] = f2bs(acc[cb][r]);
            }
        }
    if ((w == 0 || w == 2) && hi == 0) {
        size_t mb = (((size_t)half * B_DIM + b) * 2) * N_DIM;
        ms[mb + i] = mrun;
        ms[mb + N_DIM + i] = srun;
    }
}

// ---------------------------------------------------------------------------
// Kernel 3: flash-merge of the two key-halves + gamma/residual epilogue.
// out = g * (O0*w0 + O1*w1) / (s0*w0 + s1*w1) + x,  w_h = 2^(m_h - max)
// ---------------------------------------------------------------------------
__global__ __launch_bounds__(256)
void merge_kernel(const short* __restrict__ Op, const float* __restrict__ ms,
                  const float* __restrict__ x, const float* __restrict__ gamma,
                  float* __restrict__ out)
{
    size_t base = ((size_t)blockIdx.x * 256 + threadIdx.x) * 8;
    int n = (int)(base & (N_DIM - 1));
    int b = (int)(base >> 20);                     // 256*4096 = 2^20 per batch
    const size_t HSZ = (size_t)B_DIM * C_DIM * N_DIM;

    s16x8 o0 = *(const s16x8*)&Op[base];
    s16x8 o1 = *(const s16x8*)&Op[HSZ + base];

    size_t m0o = ((size_t)b * 2) * N_DIM + n;
    size_t m1o = (((size_t)B_DIM + b) * 2) * N_DIM + n;
    f32x4 m0a = *(const f32x4*)&ms[m0o];
    f32x4 m0b = *(const f32x4*)&ms[m0o + 4];
    f32x4 s0a = *(const f32x4*)&ms[m0o + N_DIM];
    f32x4 s0b = *(const f32x4*)&ms[m0o + N_DIM + 4];
    f32x4 m1a = *(const f32x4*)&ms[m1o];
    f32x4 m1b = *(const f32x4*)&ms[m1o + 4];
    f32x4 s1a = *(const f32x4*)&ms[m1o + N_DIM];
    f32x4 s1b = *(const f32x4*)&ms[m1o + N_DIM + 4];

    f32x4 xa = *(const f32x4*)&x[base];
    f32x4 xb = *(const f32x4*)&x[base + 4];
    float g = gamma[0];

    f32x4 ra, rb;
    #pragma unroll
    for (int e = 0; e < 4; ++e) {
        float m = fmaxf(m0a[e], m1a[e]);
        float w0 = exp2f(m0a[e] - m), w1 = exp2f(m1a[e] - m);
        float den = s0a[e] * w0 + s1a[e] * w1;
        float o = (bs2f(o0[e]) * w0 + bs2f(o1[e]) * w1) / den;
        ra[e] = g * o + xa[e];
    }
    #pragma unroll
    for (int e = 0; e < 4; ++e) {
        float m = fmaxf(m0b[e], m1b[e]);
        float w0 = exp2f(m0b[e] - m), w1 = exp2f(m1b[e] - m);
        float den = s0b[e] * w0 + s1b[e] * w1;
        float o = (bs2f(o0[e + 4]) * w0 + bs2f(o1[e + 4]) * w1) / den;
        rb[e] = g * o + xb[e];
    }
    *(f32x4*)&out[base] = ra;
    *(f32x4*)&out[base + 4] = rb;
}

// ---------------------------------------------------------------------------
extern "C" void kernel_launch(void* const* d_in, const int* in_sizes, int n_in,
                              void* d_out, int out_size, void* d_ws, size_t ws_size,
                              hipStream_t stream) {
    const float* x  = (const float*)d_in[0];
    const float* y  = (const float*)d_in[1];
    const float* wq = (const float*)d_in[2];
    const float* wk = (const float*)d_in[3];
    const float* wv = (const float*)d_in[4];
    const float* gm = (const float*)d_in[5];
    float* out = (float*)d_out;

    char* ws = (char*)d_ws;
    const size_t SZ = (size_t)B_DIM * N_DIM * C_DIM * sizeof(short); // 8 MB
    short* xT = (short*)(ws);
    short* yT = (short*)(ws + SZ);
    short* Qb = (short*)(ws + 2 * SZ);
    short* Kb = (short*)(ws + 3 * SZ);
    short* Vb = (short*)(ws + 4 * SZ);
    short* wb = (short*)(ws + 5 * SZ); // 384 KB, dead after proj
    // overlays (dead after proj_kernel):
    short* Op = xT;                    // [2][B][C][N] bf16 = 16 MB (xT+yT)
    float* ms = (float*)wb;            // [2][B][2][N] f32 = 256 KB

    prep_kernel<<<dim3(2048 + 96), dim3(256), 0, stream>>>(x, y, wq, wk, wv, xT, yT, wb);
    proj_kernel<<<dim3(3072), dim3(256), 0, stream>>>(xT, yT, wb, Qb, Kb, Vb);
    attn_kernel<<<dim3(512), dim3(512), 0, stream>>>(Qb, Kb, Vb, Op, ms);
    merge_kernel<<<dim3(2048), dim3(256), 0, stream>>>(Op, ms, x, gm, out);
}

// Round 6
// 204.080 us; speedup vs baseline: 2.0415x; 1.0059x over previous
//
#include <hip/hip_runtime.h>
#include <hip/hip_bf16.h>
#include <stdint.h>

#define C_DIM 256
#define N_DIM 4096
#define B_DIM 4

typedef __attribute__((ext_vector_type(8))) short s16x8;   // 8 bf16
typedef __attribute__((ext_vector_type(4))) short s16x4;   // 4 bf16
typedef __attribute__((ext_vector_type(4))) float f32x4;
typedef __attribute__((ext_vector_type(16))) float f32x16;

static __device__ __forceinline__ short f2bs(float f) {
    __bf16 h = (__bf16)f;                 // RNE f32->bf16
    return __builtin_bit_cast(short, h);
}

// async global->LDS DMA, 16B per lane; LDS dest = wave-uniform base + lane*16
static __device__ __forceinline__ void g2l16(const short* g, short* l) {
    __builtin_amdgcn_global_load_lds(
        (const __attribute__((address_space(1))) unsigned int*)g,
        (__attribute__((address_space(3))) unsigned int*)l, 16, 0, 0);
}

// ---------------------------------------------------------------------------
// Kernel 0: transpose+convert x,y -> xT,yT [B][N][C] bf16; convert weights.
// ---------------------------------------------------------------------------
__global__ __launch_bounds__(256)
void prep_kernel(const float* __restrict__ x, const float* __restrict__ y,
                 const float* __restrict__ wq, const float* __restrict__ wk,
                 const float* __restrict__ wv,
                 short* __restrict__ xT, short* __restrict__ yT,
                 short* __restrict__ wb)
{
    int bid = blockIdx.x;
    int t = threadIdx.x;
    if (bid < 2048) {
        const float* src = (bid < 1024) ? x : y;
        short* dst = (bid < 1024) ? xT : yT;
        int id = bid & 1023;
        int ct = id & 3;            // 4 c-tiles of 64
        int nt = (id >> 2) & 63;    // 64 n-tiles of 64
        int b  = id >> 8;           // 4 batches
        int n0 = nt * 64, c0 = ct * 64;
        __shared__ short T[64][66]; // odd dword stride -> conflict-free
        int l = t & 63;
        int wv_ = t >> 6;
        #pragma unroll
        for (int p = 0; p < 16; ++p) {
            int c = wv_ + p * 4;
            float v = src[((size_t)(b * C_DIM + c0 + c)) * N_DIM + n0 + l];
            T[l][c] = f2bs(v);
        }
        __syncthreads();
        #pragma unroll
        for (int p = 0; p < 16; ++p) {
            int n = wv_ + p * 4;
            dst[((size_t)(b * N_DIM + n0 + n)) * C_DIM + c0 + l] = T[n][l];
        }
    } else {
        // weights: 96 blocks x 2048 elems
        int id = bid - 2048;
        const float* w = (id < 32) ? wq : (id < 64) ? wk : wv;
        short* dst = wb + (size_t)(id / 32) * (C_DIM * C_DIM);
        int off = (id & 31) * 2048 + t * 8;
        f32x4 a  = *(const f32x4*)(w + off);
        f32x4 b4 = *(const f32x4*)(w + off + 4);
        s16x8 r;
        r[0]=f2bs(a[0]);  r[1]=f2bs(a[1]);  r[2]=f2bs(a[2]);  r[3]=f2bs(a[3]);
        r[4]=f2bs(b4[0]); r[5]=f2bs(b4[1]); r[6]=f2bs(b4[2]); r[7]=f2bs(b4[3]);
        *(s16x8*)(dst + off) = r;
    }
}

// ---------------------------------------------------------------------------
// Kernel 1: projections. Qb,Kb = [B][N][256]; Vb = [B][256][N].
// Q is pre-scaled by log2(e) so attention softmax can use exp2 directly.
// ---------------------------------------------------------------------------
__global__ __launch_bounds__(256)
void proj_kernel(const short* __restrict__ xT, const short* __restrict__ yT,
                 const short* __restrict__ wb,
                 short* __restrict__ Qb, short* __restrict__ Kb,
                 short* __restrict__ Vb)
{
    int bid = blockIdx.x;              // 3072 = 12 * 64 * 4
    int ot = bid & 3;
    int nt = (bid >> 2) & 63;
    int bp = bid >> 8;                 // 0..11 = b*3 + p
    int b = bp / 3, p = bp % 3;
    int n0 = nt * 64, o0 = ot * 64;
    const short* src = (p == 0) ? xT : yT;
    const short* w = wb + (size_t)p * C_DIM * C_DIM;

    __shared__ __align__(16) short Xs[64][264];

    int t = threadIdx.x;
    const short* srcb = src + (size_t)(b * N_DIM + n0) * C_DIM;
    #pragma unroll
    for (int pas = 0; pas < 8; ++pas) {
        int slot = pas * 256 + t;
        int row = slot >> 5, ck = slot & 31;
        *(s16x8*)&Xs[row][ck * 8] = *(const s16x8*)&srcb[(size_t)row * C_DIM + ck * 8];
    }
    __syncthreads();

    int lane = t & 63;
    int wid = t >> 6;
    int m = lane & 15, q = lane >> 4;
    f32x4 acc[4] = {};

    if (p < 2) {
        #pragma unroll
        for (int kk = 0; kk < 8; ++kk) {
            s16x8 af = *(const s16x8*)&Xs[wid * 16 + m][kk * 32 + q * 8];
            #pragma unroll
            for (int ob = 0; ob < 4; ++ob) {
                s16x8 bf = *(const s16x8*)&w[(size_t)(o0 + ob * 16 + m) * C_DIM + kk * 32 + q * 8];
                acc[ob] = __builtin_amdgcn_mfma_f32_16x16x32_bf16(af, bf, acc[ob], 0, 0, 0);
            }
        }
        float sc = (p == 0) ? 1.4426950408889634f : 1.0f;  // log2(e) for Q
        short* dst = ((p == 0) ? Qb : Kb) + (size_t)b * N_DIM * C_DIM;
        #pragma unroll
        for (int ob = 0; ob < 4; ++ob)
            #pragma unroll
            for (int r = 0; r < 4; ++r) {
                int n = n0 + wid * 16 + q * 4 + r;
                int o = o0 + ob * 16 + m;
                dst[(size_t)n * C_DIM + o] = f2bs(acc[ob][r] * sc);
            }
    } else {
        #pragma unroll
        for (int kk = 0; kk < 8; ++kk) {
            s16x8 af = *(const s16x8*)&w[(size_t)(o0 + wid * 16 + m) * C_DIM + kk * 32 + q * 8];
            #pragma unroll
            for (int nb = 0; nb < 4; ++nb) {
                s16x8 bf = *(const s16x8*)&Xs[nb * 16 + m][kk * 32 + q * 8];
                acc[nb] = __builtin_amdgcn_mfma_f32_16x16x32_bf16(af, bf, acc[nb], 0, 0, 0);
            }
        }
        short* dst = Vb + (size_t)b * C_DIM * N_DIM;
        #pragma unroll
        for (int nb = 0; nb < 4; ++nb)
            #pragma unroll
            for (int r = 0; r < 4; ++r) {
                int o = o0 + wid * 16 + q * 4 + r;
                int n = n0 + nb * 16 + m;
                dst[(size_t)o * N_DIM + n] = f2bs(acc[nb][r]);
            }
    }
}

// ---------------------------------------------------------------------------
// Kernel 2: flash attention + epilogue. R0 structure (best measured) with:
//  - K/V staged by global_load_lds DMA into double-buffered LINEAR LDS
//    (no staging regs, no ds_write phase, no VALU staging cost)
//  - source-pre-swizzled layout: LDS granule g of row r holds global granule
//    g^(r&7); reads XOR the same key -> conflict-free despite power-of-2 rows
//  - raw s_barrier + lgkmcnt(0); vmcnt(0) drained ONCE per jt (end of C) so
//    the DMA issued in A(jt) has a full iteration to land before A(jt+1)
// Waves 0-3 "QK" (ib=w>>1, jb=w&1): S^T = mfma(K rows, Q cols), softmax
// partials, PV c-strip of 32. Waves 4-7: 3 PV c-strips each.
// ---------------------------------------------------------------------------
__global__ __launch_bounds__(512, 2)
void attn_kernel(const short* __restrict__ Qb, const short* __restrict__ Kb,
                 const short* __restrict__ Vb, const float* __restrict__ x,
                 const float* __restrict__ gamma, float* __restrict__ out)
{
    int bid0 = blockIdx.x;
    int bid = (bid0 & 7) * 32 + (bid0 >> 3);   // XCD swizzle: 32 same-batch blocks/XCD
    int b = bid >> 6, it = bid & 63;
    int i0 = it * 64;

    int t = threadIdx.x;
    int w = t >> 6;
    int lane = t & 63;
    int il = lane & 31;
    int hi = lane >> 5;
    int xsw = il & 7;                          // read-side swizzle key

    bool isQK = (w < 4);
    int ib = isQK ? (w >> 1) : ((w - 4) >> 1);
    int jb = w & 1;                                  // QK waves only
    int cbase = isQK ? ((w & 1) * 32) : (64 + (w & 1) * 96);
    int ncb = isQK ? 1 : 3;

    __shared__ __align__(16) short Ks[2][64][256];   // 64 KB, linear (DMA dest)
    __shared__ __align__(16) short Vs[2][256][64];   // 64 KB, linear (DMA dest)
    __shared__ __align__(16) short Ps[64][72];       //  9.2 KB (pad ok, VALU-written)
    __shared__ float mpart[2][64];
    __shared__ float spart[2][64];                   // total ~139 KB

    const short* Qp = Qb + (size_t)b * N_DIM * C_DIM;
    const short* Kp = Kb + (size_t)b * N_DIM * C_DIM;
    const short* Vp = Vb + (size_t)b * C_DIM * N_DIM;

    // Q fragments: B[k=c][col=q], lane holds q = ib*32+il, k = kk*16+hi*8+e
    s16x8 qf[16];
    if (isQK) {
        const short* qrow = Qp + (size_t)(i0 + ib * 32 + il) * C_DIM + hi * 8;
        #pragma unroll
        for (int kk = 0; kk < 16; ++kk)
            qf[kk] = *(const s16x8*)&qrow[kk * 16];
    }

    // prologue: DMA tile 0 into buffer 0 (src pre-swizzled per row)
    #pragma unroll
    for (int p = 0; p < 4; ++p) {
        int kr = w * 8 + 2 * p + (lane >> 5);              // row this lane feeds
        int gs = (lane & 31) ^ (kr & 7);                   // pre-swizzled granule
        g2l16(Kp + (size_t)kr * C_DIM + gs * 8, &Ks[0][w * 8 + 2 * p][0]);
    }
    #pragma unroll
    for (int p = 0; p < 4; ++p) {
        int vr = w * 32 + 8 * p + (lane >> 3);
        int gs = (lane & 7) ^ (vr & 7);
        g2l16(Vp + (size_t)vr * N_DIM + gs * 8, &Vs[0][w * 32 + 8 * p][0]);
    }
    asm volatile("s_waitcnt vmcnt(0) lgkmcnt(0)" ::: "memory");
    __builtin_amdgcn_s_barrier();

    f32x16 acc[3] = {};
    float mrun = -3e38f, srun = 0.f;
    int cur = 0;

    for (int jt = 0; jt < 64; ++jt) {
        bool pf = (jt < 63);
        int nx = cur ^ 1;

        // ---- Phase A: issue DMA(jt+1 -> nx); QK MFMA + max partial --------
        if (pf) {
            int j1 = (jt + 1) * 64;
            const short* kg = Kp + (size_t)j1 * C_DIM;
            #pragma unroll
            for (int p = 0; p < 4; ++p) {
                int kr = w * 8 + 2 * p + (lane >> 5);
                int gs = (lane & 31) ^ (kr & 7);
                g2l16(kg + (size_t)kr * C_DIM + gs * 8, &Ks[nx][w * 8 + 2 * p][0]);
            }
            const short* vg = Vp + j1;
            #pragma unroll
            for (int p = 0; p < 4; ++p) {
                int vr = w * 32 + 8 * p + (lane >> 3);
                int gs = (lane & 7) ^ (vr & 7);
                g2l16(vg + (size_t)vr * N_DIM + gs * 8, &Vs[nx][w * 32 + 8 * p][0]);
            }
        }
        f32x16 sv;
        if (isQK) {
            f32x16 sv0 = {}, sv1 = {};
            __builtin_amdgcn_s_setprio(1);
            #pragma unroll
            for (int kk = 0; kk < 8; ++kk) {
                s16x8 a0 = *(const s16x8*)&Ks[cur][jb * 32 + il][((2 * kk + hi) ^ xsw) * 8];
                sv0 = __builtin_amdgcn_mfma_f32_32x32x16_bf16(a0, qf[kk], sv0, 0, 0, 0);
                s16x8 a1 = *(const s16x8*)&Ks[cur][jb * 32 + il][((2 * (kk + 8) + hi) ^ xsw) * 8];
                sv1 = __builtin_amdgcn_mfma_f32_32x32x16_bf16(a1, qf[kk + 8], sv1, 0, 0, 0);
            }
            __builtin_amdgcn_s_setprio(0);
            #pragma unroll
            for (int r = 0; r < 16; ++r) sv[r] = sv0[r] + sv1[r];
            float tmax = sv[0];
            #pragma unroll
            for (int r = 1; r < 16; ++r) tmax = fmaxf(tmax, sv[r]);
            tmax = fmaxf(tmax, __shfl_xor(tmax, 32, 64));
            if (hi == 0) mpart[jb][ib * 32 + il] = tmax;
        }
        asm volatile("s_waitcnt lgkmcnt(0)" ::: "memory");
        __builtin_amdgcn_s_barrier();     // bar1: mpart ready; Ks[cur] reads done

        // ---- Phase B: softmax + P/spart write; acc rescale ----------------
        float mnew = fmaxf(mrun, fmaxf(mpart[0][ib * 32 + il], mpart[1][ib * 32 + il]));
        float alpha = exp2f(mrun - mnew);
        mrun = mnew;
        if (isQK) {
            float ts = 0.f;
            #pragma unroll
            for (int r = 0; r < 16; ++r) {
                float pe = exp2f(sv[r] - mnew);   // Q pre-scaled by log2(e)
                sv[r] = pe;
                ts += pe;
            }
            ts += __shfl_xor(ts, 32, 64);
            if (hi == 0) spart[jb][ib * 32 + il] = ts;
            // P rows j = jb*32 + 8g + 4hi + (0..3), col q = il -> Ps[q][j]
            #pragma unroll
            for (int g = 0; g < 4; ++g) {
                s16x4 pv;
                pv[0] = f2bs(sv[4 * g + 0]); pv[1] = f2bs(sv[4 * g + 1]);
                pv[2] = f2bs(sv[4 * g + 2]); pv[3] = f2bs(sv[4 * g + 3]);
                *(s16x4*)&Ps[ib * 32 + il][jb * 32 + g * 8 + hi * 4] = pv;
            }
        }
        if (__any(alpha != 1.f)) {          // T13: skip rescale if max unchanged
            #pragma unroll
            for (int cb = 0; cb < 3; ++cb)
                if (cb < ncb) {
                    #pragma unroll
                    for (int r = 0; r < 16; ++r) acc[cb][r] *= alpha;
                }
        }
        asm volatile("s_waitcnt lgkmcnt(0)" ::: "memory");
        __builtin_amdgcn_s_barrier();     // bar2: Ps + spart ready

        // ---- Phase C: PV; drain DMA once, swap buffers --------------------
        srun = srun * alpha + spart[0][ib * 32 + il] + spart[1][ib * 32 + il];
        __builtin_amdgcn_s_setprio(1);
        #pragma unroll
        for (int kc = 0; kc < 4; ++kc) {
            s16x8 bf = *(const s16x8*)&Ps[ib * 32 + il][kc * 16 + hi * 8];
            #pragma unroll
            for (int cb = 0; cb < 3; ++cb)
                if (cb < ncb) {
                    s16x8 af = *(const s16x8*)&Vs[cur][cbase + cb * 32 + il][((2 * kc + hi) ^ xsw) * 8];
                    acc[cb] = __builtin_amdgcn_mfma_f32_32x32x16_bf16(af, bf, acc[cb], 0, 0, 0);
                }
        }
        __builtin_amdgcn_s_setprio(0);
        asm volatile("s_waitcnt vmcnt(0) lgkmcnt(0)" ::: "memory");
        __builtin_amdgcn_s_barrier();     // bar3: DMA(jt+1) landed; Vs/Ps reads done
        cur ^= 1;
    }

    // epilogue: O^T layout -> out[b][c][i], residual + gamma scale
    float g = gamma[0];
    float inv = 1.f / srun;
    int i = i0 + ib * 32 + il;
    #pragma unroll
    for (int cb = 0; cb < 3; ++cb)
        if (cb < ncb) {
            #pragma unroll
            for (int r = 0; r < 16; ++r) {
                int c = cbase + cb * 32 + (r & 3) + 8 * (r >> 2) + 4 * hi;
                size_t idx = ((size_t)(b * C_DIM + c)) * N_DIM + i;
                out[idx] = g * acc[cb][r] * inv + x[idx];
            }
        }
}

// ---------------------------------------------------------------------------
extern "C" void kernel_launch(void* const* d_in, const int* in_sizes, int n_in,
                              void* d_out, int out_size, void* d_ws, size_t ws_size,
                              hipStream_t stream) {
    const float* x  = (const float*)d_in[0];
    const float* y  = (const float*)d_in[1];
    const float* wq = (const float*)d_in[2];
    const float* wk = (const float*)d_in[3];
    const float* wv = (const float*)d_in[4];
    const float* gm = (const float*)d_in[5];
    float* out = (float*)d_out;

    char* ws = (char*)d_ws;
    const size_t SZ = (size_t)B_DIM * N_DIM * C_DIM * sizeof(short); // 8 MB
    short* xT = (short*)(ws);
    short* yT = (short*)(ws + SZ);
    short* Qb = (short*)(ws + 2 * SZ);
    short* Kb = (short*)(ws + 3 * SZ);
    short* Vb = (short*)(ws + 4 * SZ);
    short* wb = (short*)(ws + 5 * SZ); // 384 KB

    prep_kernel<<<dim3(2048 + 96), dim3(256), 0, stream>>>(x, y, wq, wk, wv, xT, yT, wb);
    proj_kernel<<<dim3(3072), dim3(256), 0, stream>>>(xT, yT, wb, Qb, Kb, Vb);
    attn_kernel<<<dim3(256), dim3(512), 0, stream>>>(Qb, Kb, Vb, x, gm, out);
}

// Round 7
// 165.704 us; speedup vs baseline: 2.5142x; 1.2316x over previous
//
#include <hip/hip_runtime.h>
#include <hip/hip_bf16.h>
#include <stdint.h>

#define C_DIM 256
#define N_DIM 4096
#define B_DIM 4

typedef __attribute__((ext_vector_type(8))) short s16x8;   // 8 bf16
typedef __attribute__((ext_vector_type(4))) short s16x4;   // 4 bf16
typedef __attribute__((ext_vector_type(4))) float f32x4;
typedef __attribute__((ext_vector_type(16))) float f32x16;
typedef __attribute__((ext_vector_type(4))) int i32x4;

static __device__ __forceinline__ short f2bs(float f) {
    __bf16 h = (__bf16)f;                 // RNE f32->bf16
    return __builtin_bit_cast(short, h);
}
static __device__ __forceinline__ float bs2f(short s) {
    unsigned int u = ((unsigned int)(unsigned short)s) << 16;
    return __builtin_bit_cast(float, u);
}
static __device__ __forceinline__ unsigned cvtpk(float lo, float hi) {
    unsigned r;
    asm("v_cvt_pk_bf16_f32 %0, %1, %2" : "=v"(r) : "v"(lo), "v"(hi));
    return r;
}
// v_permlane32_swap_b32: a' = {a.lo32lanes, b.lo32lanes}; b' = {a.hi, b.hi}
static __device__ __forceinline__ void plswap(unsigned &a, unsigned &b) {
    asm("v_permlane32_swap_b32 %0, %1" : "+v"(a), "+v"(b));
}

// ---------------------------------------------------------------------------
// Kernel 0: transpose+convert x,y -> xT,yT [B][N][C] bf16; convert weights.
// ---------------------------------------------------------------------------
__global__ __launch_bounds__(256)
void prep_kernel(const float* __restrict__ x, const float* __restrict__ y,
                 const float* __restrict__ wq, const float* __restrict__ wk,
                 const float* __restrict__ wv,
                 short* __restrict__ xT, short* __restrict__ yT,
                 short* __restrict__ wb)
{
    int bid = blockIdx.x;
    int t = threadIdx.x;
    if (bid < 2048) {
        const float* src = (bid < 1024) ? x : y;
        short* dst = (bid < 1024) ? xT : yT;
        int id = bid & 1023;
        int ct = id & 3;            // 4 c-tiles of 64
        int nt = (id >> 2) & 63;    // 64 n-tiles of 64
        int b  = id >> 8;           // 4 batches
        int n0 = nt * 64, c0 = ct * 64;
        __shared__ short T[64][66]; // odd dword stride -> conflict-free
        int l = t & 63;
        int wv_ = t >> 6;
        #pragma unroll
        for (int p = 0; p < 16; ++p) {
            int c = wv_ + p * 4;
            float v = src[((size_t)(b * C_DIM + c0 + c)) * N_DIM + n0 + l];
            T[l][c] = f2bs(v);
        }
        __syncthreads();
        #pragma unroll
        for (int p = 0; p < 16; ++p) {
            int n = wv_ + p * 4;
            dst[((size_t)(b * N_DIM + n0 + n)) * C_DIM + c0 + l] = T[n][l];
        }
    } else {
        // weights: 96 blocks x 2048 elems
        int id = bid - 2048;
        const float* w = (id < 32) ? wq : (id < 64) ? wk : wv;
        short* dst = wb + (size_t)(id / 32) * (C_DIM * C_DIM);
        int off = (id & 31) * 2048 + t * 8;
        f32x4 a  = *(const f32x4*)(w + off);
        f32x4 b4 = *(const f32x4*)(w + off + 4);
        s16x8 r;
        r[0]=f2bs(a[0]);  r[1]=f2bs(a[1]);  r[2]=f2bs(a[2]);  r[3]=f2bs(a[3]);
        r[4]=f2bs(b4[0]); r[5]=f2bs(b4[1]); r[6]=f2bs(b4[2]); r[7]=f2bs(b4[3]);
        *(s16x8*)(dst + off) = r;
    }
}

// ---------------------------------------------------------------------------
// Kernel 1: projections. Qb,Kb = [B][N][256]; Vb = [B][256][N].
// Q is pre-scaled by log2(e) so attention softmax can use exp2 directly.
// ---------------------------------------------------------------------------
__global__ __launch_bounds__(256)
void proj_kernel(const short* __restrict__ xT, const short* __restrict__ yT,
                 const short* __restrict__ wb,
                 short* __restrict__ Qb, short* __restrict__ Kb,
                 short* __restrict__ Vb)
{
    int bid = blockIdx.x;              // 3072 = 12 * 64 * 4
    int ot = bid & 3;
    int nt = (bid >> 2) & 63;
    int bp = bid >> 8;                 // 0..11 = b*3 + p
    int b = bp / 3, p = bp % 3;
    int n0 = nt * 64, o0 = ot * 64;
    const short* src = (p == 0) ? xT : yT;
    const short* w = wb + (size_t)p * C_DIM * C_DIM;

    __shared__ __align__(16) short Xs[64][264];

    int t = threadIdx.x;
    const short* srcb = src + (size_t)(b * N_DIM + n0) * C_DIM;
    #pragma unroll
    for (int pas = 0; pas < 8; ++pas) {
        int slot = pas * 256 + t;
        int row = slot >> 5, ck = slot & 31;
        *(s16x8*)&Xs[row][ck * 8] = *(const s16x8*)&srcb[(size_t)row * C_DIM + ck * 8];
    }
    __syncthreads();

    int lane = t & 63;
    int wid = t >> 6;
    int m = lane & 15, q = lane >> 4;
    f32x4 acc[4] = {};

    if (p < 2) {
        #pragma unroll
        for (int kk = 0; kk < 8; ++kk) {
            s16x8 af = *(const s16x8*)&Xs[wid * 16 + m][kk * 32 + q * 8];
            #pragma unroll
            for (int ob = 0; ob < 4; ++ob) {
                s16x8 bf = *(const s16x8*)&w[(size_t)(o0 + ob * 16 + m) * C_DIM + kk * 32 + q * 8];
                acc[ob] = __builtin_amdgcn_mfma_f32_16x16x32_bf16(af, bf, acc[ob], 0, 0, 0);
            }
        }
        float sc = (p == 0) ? 1.4426950408889634f : 1.0f;  // log2(e) for Q
        short* dst = ((p == 0) ? Qb : Kb) + (size_t)b * N_DIM * C_DIM;
        #pragma unroll
        for (int ob = 0; ob < 4; ++ob)
            #pragma unroll
            for (int r = 0; r < 4; ++r) {
                int n = n0 + wid * 16 + q * 4 + r;
                int o = o0 + ob * 16 + m;
                dst[(size_t)n * C_DIM + o] = f2bs(acc[ob][r] * sc);
            }
    } else {
        #pragma unroll
        for (int kk = 0; kk < 8; ++kk) {
            s16x8 af = *(const s16x8*)&w[(size_t)(o0 + wid * 16 + m) * C_DIM + kk * 32 + q * 8];
            #pragma unroll
            for (int nb = 0; nb < 4; ++nb) {
                s16x8 bf = *(const s16x8*)&Xs[nb * 16 + m][kk * 32 + q * 8];
                acc[nb] = __builtin_amdgcn_mfma_f32_16x16x32_bf16(af, bf, acc[nb], 0, 0, 0);
            }
        }
        short* dst = Vb + (size_t)b * C_DIM * N_DIM;
        #pragma unroll
        for (int nb = 0; nb < 4; ++nb)
            #pragma unroll
            for (int r = 0; r < 4; ++r) {
                int o = o0 + wid * 16 + q * 4 + r;
                int n = n0 + nb * 16 + m;
                dst[(size_t)o * N_DIM + n] = f2bs(acc[nb][r]);
            }
    }
}

// ---------------------------------------------------------------------------
// Kernel 2: WAVE-INDEPENDENT flash attention, ksplit=4.
// Grid 512 x 256thr (4 waves); each wave owns 32 q-rows END-TO-END:
//   QK (swapped: A=K rows, B=Q cols -> per-lane P rows, R0-proven layout),
//   softmax fully in registers, P->bf16 PV B-fragments via
//   v_cvt_pk_bf16_f32 + v_permlane32_swap_b32 (T12; no P in LDS),
//   PV over all 256 channels (acc 8x f32x16).
// LDS: single-buffered Ks[32][264]+Vs[256][40] = 37.4 KB (padded strides,
// R0-proven conflict-free) -> 2 blocks/CU co-resident; 2 barriers/tile,
// stage-writes between them; loads issued mid-compute (T14).
// Partials: ks 0/1 -> Op01 (dead xT/yT); ks 2/3 -> packed bf16 pairs inside
// out's f32 slots (disjoint 2B stores). merge_kernel normalizes.
// ---------------------------------------------------------------------------
__global__ __launch_bounds__(256, 2)
void attn_kernel(const short* __restrict__ Qb, const short* __restrict__ Kb,
                 const short* __restrict__ Vb,
                 short* __restrict__ Op01, short* __restrict__ Op23,
                 float* __restrict__ ms)
{
    int bid0 = blockIdx.x;
    int swz = (bid0 & 7) * 64 + (bid0 >> 3);   // XCD swizzle: 64 blocks/XCD
    int b  = swz >> 7;                          // share one (b, 2 ks) K/V set
    int ks = (swz >> 5) & 3;
    int qt = swz & 31;
    int i0 = qt * 128;

    int t = threadIdx.x;
    int wv = t >> 6;
    int lane = t & 63;
    int il = lane & 31, hi = lane >> 5;
    int q0 = i0 + wv * 32;

    __shared__ __align__(16) short Ksh[32][264];   // 16.9 KB
    __shared__ __align__(16) short Vsh[256][40];   // 20.5 KB

    const short* Qp = Qb + (size_t)b * N_DIM * C_DIM;
    const short* Kp = Kb + (size_t)b * N_DIM * C_DIM + (size_t)(ks * 1024) * C_DIM;
    const short* Vp = Vb + (size_t)b * C_DIM * N_DIM + ks * 1024;

    // Q fragments: B[k=c][col=q], lane holds q = q0+il, c = kk*16+hi*8+e
    s16x8 qf[16];
    {
        const short* qrow = Qp + (size_t)(q0 + il) * C_DIM + hi * 8;
        #pragma unroll
        for (int kk = 0; kk < 16; ++kk)
            qf[kk] = *(const s16x8*)&qrow[kk * 16];
    }

    // staging maps (256 threads): K tile 32x256, V tile 256x32, 4x16B each
    int krb = t >> 5, kck = t & 31;   // K rows p*8+krb
    int vrb = t >> 2, vck = t & 3;    // V rows p*64+vrb

    // prologue: stage tile 0
    {
        s16x8 kr[4], vr[4];
        #pragma unroll
        for (int p = 0; p < 4; ++p)
            kr[p] = *(const s16x8*)&Kp[(size_t)(p * 8 + krb) * C_DIM + kck * 8];
        #pragma unroll
        for (int p = 0; p < 4; ++p)
            vr[p] = *(const s16x8*)&Vp[(size_t)(p * 64 + vrb) * N_DIM + vck * 8];
        #pragma unroll
        for (int p = 0; p < 4; ++p) *(s16x8*)&Ksh[p * 8 + krb][kck * 8] = kr[p];
        #pragma unroll
        for (int p = 0; p < 4; ++p) *(s16x8*)&Vsh[p * 64 + vrb][vck * 8] = vr[p];
    }
    __syncthreads();

    f32x16 acc[8] = {};               // O^T[c = cs*32+crow(r,hi)][q = il]
    float mrun = -1e30f, srun = 0.f;

    for (int jt = 0; jt < 32; ++jt) {
        bool pfch = (jt < 31);

        // ---- QK: 2 independent 8-chains --------------------------------
        f32x16 sv0 = {}, sv1 = {};
        __builtin_amdgcn_s_setprio(1);
        #pragma unroll
        for (int kk = 0; kk < 8; ++kk) {
            s16x8 a0 = *(const s16x8*)&Ksh[il][kk * 16 + hi * 8];
            sv0 = __builtin_amdgcn_mfma_f32_32x32x16_bf16(a0, qf[kk], sv0, 0, 0, 0);
            s16x8 a1 = *(const s16x8*)&Ksh[il][(kk + 8) * 16 + hi * 8];
            sv1 = __builtin_amdgcn_mfma_f32_32x32x16_bf16(a1, qf[kk + 8], sv1, 0, 0, 0);
        }
        __builtin_amdgcn_s_setprio(0);
        #pragma unroll
        for (int r = 0; r < 16; ++r) sv0[r] += sv1[r];

        // ---- in-register softmax (T13 defer-max, THR=8 in log2 units) ---
        float tmax = sv0[0];
        #pragma unroll
        for (int r = 1; r < 16; ++r) tmax = fmaxf(tmax, sv0[r]);
        tmax = fmaxf(tmax, __shfl_xor(tmax, 32, 64));
        if (__any(tmax > mrun + 8.f)) {
            float mnew = fmaxf(mrun, tmax);
            float alpha = exp2f(mrun - mnew);
            mrun = mnew;
            srun *= alpha;
            #pragma unroll
            for (int cs = 0; cs < 8; ++cs)
                #pragma unroll
                for (int r = 0; r < 16; ++r) acc[cs][r] *= alpha;
        }
        // issue K prefetch (latency hides under softmax+PV)
        s16x8 kr[4];
        if (pfch) {
            const short* kg = Kp + (size_t)((jt + 1) * 32) * C_DIM;
            #pragma unroll
            for (int p = 0; p < 4; ++p)
                kr[p] = *(const s16x8*)&kg[(size_t)(p * 8 + krb) * C_DIM + kck * 8];
        }
        float ts = 0.f;
        #pragma unroll
        for (int r = 0; r < 16; ++r) {
            float pe = exp2f(sv0[r] - mrun);   // Q pre-scaled by log2(e)
            sv0[r] = pe;
            ts += pe;
        }
        ts += __shfl_xor(ts, 32, 64);
        srun += ts;

        // ---- P -> bf16 PV B-fragments (cvt_pk + permlane32_swap) --------
        // lane (il,hi) holds P[q=il][k=crow(r,hi)], crow = (r&3)+8(r>>2)+4hi.
        // quad rq holds k in [8rq+4hi, 8rq+4hi+3]. After swap of (rq,rq+1)
        // register pairs, frag(s) covers k = 16s+8hi+e  (e = 0..7).
        unsigned d0[4], d1[4];
        #pragma unroll
        for (int rq = 0; rq < 4; ++rq) {
            d0[rq] = cvtpk(sv0[4 * rq + 0], sv0[4 * rq + 1]);
            d1[rq] = cvtpk(sv0[4 * rq + 2], sv0[4 * rq + 3]);
        }
        unsigned w0a = d0[0], w2a = d0[1]; plswap(w0a, w2a);
        unsigned w1a = d1[0], w3a = d1[1]; plswap(w1a, w3a);
        unsigned w0b = d0[2], w2b = d0[3]; plswap(w0b, w2b);
        unsigned w1b = d1[2], w3b = d1[3]; plswap(w1b, w3b);
        i32x4 pi0 = { (int)w0a, (int)w1a, (int)w2a, (int)w3a };
        i32x4 pi1 = { (int)w0b, (int)w1b, (int)w2b, (int)w3b };
        s16x8 pf0 = __builtin_bit_cast(s16x8, pi0);   // keys 0..15 of tile
        s16x8 pf1 = __builtin_bit_cast(s16x8, pi1);   // keys 16..31

        // issue V prefetch
        s16x8 vr[4];
        if (pfch) {
            const short* vg = Vp + (jt + 1) * 32;
            #pragma unroll
            for (int p = 0; p < 4; ++p)
                vr[p] = *(const s16x8*)&vg[(size_t)(p * 64 + vrb) * N_DIM + vck * 8];
        }

        // ---- PV: 8 c-strips x 2 k-slices, 8 independent acc chains ------
        __builtin_amdgcn_s_setprio(1);
        #pragma unroll
        for (int cs = 0; cs < 8; ++cs) {
            s16x8 va = *(const s16x8*)&Vsh[cs * 32 + il][hi * 8];
            acc[cs] = __builtin_amdgcn_mfma_f32_32x32x16_bf16(va, pf0, acc[cs], 0, 0, 0);
            s16x8 vb = *(const s16x8*)&Vsh[cs * 32 + il][16 + hi * 8];
            acc[cs] = __builtin_amdgcn_mfma_f32_32x32x16_bf16(vb, pf1, acc[cs], 0, 0, 0);
        }
        __builtin_amdgcn_s_setprio(0);

        __syncthreads();                 // all reads of tile jt done
        if (pfch) {
            #pragma unroll
            for (int p = 0; p < 4; ++p) *(s16x8*)&Ksh[p * 8 + krb][kck * 8] = kr[p];
            #pragma unroll
            for (int p = 0; p < 4; ++p) *(s16x8*)&Vsh[p * 64 + vrb][vck * 8] = vr[p];
        }
        __syncthreads();                 // tile jt+1 staged
    }

    // ---- epilogue: unnormalized O^T partial (bf16) + per-q (m, s) -------
    int i = q0 + il;
    const size_t HSZ = (size_t)B_DIM * C_DIM * N_DIM;
    if (ks < 2) {
        short* o = Op01 + (size_t)ks * HSZ + (size_t)(b * C_DIM) * N_DIM + i;
        #pragma unroll
        for (int cs = 0; cs < 8; ++cs)
            #pragma unroll
            for (int r = 0; r < 16; ++r) {
                int c = cs * 32 + (r & 3) + 8 * (r >> 2) + 4 * hi;
                o[(size_t)c * N_DIM] = f2bs(acc[cs][r]);
            }
    } else {
        // pack as bf16 pair inside out's f32 slot: [2*idx + (ks-2)]
        short* o = Op23 + ((size_t)(b * C_DIM) * N_DIM + i) * 2 + (ks - 2);
        #pragma unroll
        for (int cs = 0; cs < 8; ++cs)
            #pragma unroll
            for (int r = 0; r < 16; ++r) {
                int c = cs * 32 + (r & 3) + 8 * (r >> 2) + 4 * hi;
                o[(size_t)c * N_DIM * 2] = f2bs(acc[cs][r]);
            }
    }
    if (hi == 0) {
        float* msp = ms + ((size_t)(ks * B_DIM + b) * 2) * N_DIM;
        msp[i] = mrun;
        msp[N_DIM + i] = srun;
    }
}

// ---------------------------------------------------------------------------
// Kernel 3: 4-way flash-merge + gamma/residual epilogue.
// out = g * (sum_h O_h w_h) / (sum_h s_h w_h) + x,  w_h = 2^(m_h - max)
// Op2/3 are read from out's own f32 slots (interleaved bf16) and then the
// slot is overwritten by the SAME thread -> race-free.
// ---------------------------------------------------------------------------
__global__ __launch_bounds__(256)
void merge_kernel(const short* __restrict__ Op01, const short* Op23,
                  const float* __restrict__ ms, const float* __restrict__ x,
                  const float* __restrict__ gamma, float* out)
{
    size_t base = ((size_t)blockIdx.x * 256 + threadIdx.x) * 8;
    int n = (int)(base & (N_DIM - 1));
    int b = (int)(base >> 20);                     // 256*4096 = 2^20 per batch
    const size_t HSZ = (size_t)B_DIM * C_DIM * N_DIM;

    s16x8 o0 = *(const s16x8*)&Op01[base];
    s16x8 o1 = *(const s16x8*)&Op01[HSZ + base];
    s16x8 pa = *(const s16x8*)&Op23[base * 2];      // n..n+3 (o2,o3 pairs)
    s16x8 pb = *(const s16x8*)&Op23[base * 2 + 8];  // n+4..n+7

    f32x4 mv[4][2], sw[4][2];
    #pragma unroll
    for (int h = 0; h < 4; ++h) {
        const float* msp = ms + ((size_t)(h * B_DIM + b) * 2) * N_DIM + n;
        mv[h][0] = *(const f32x4*)&msp[0];
        mv[h][1] = *(const f32x4*)&msp[4];
        sw[h][0] = *(const f32x4*)&msp[N_DIM];
        sw[h][1] = *(const f32x4*)&msp[N_DIM + 4];
    }
    f32x4 xa = *(const f32x4*)&x[base];
    f32x4 xb = *(const f32x4*)&x[base + 4];
    float g = gamma[0];

    float res[8];
    #pragma unroll
    for (int e = 0; e < 8; ++e) {
        int half = e >> 2, e4 = e & 3;
        float m0 = mv[0][half][e4], m1 = mv[1][half][e4];
        float m2 = mv[2][half][e4], m3 = mv[3][half][e4];
        float mm = fmaxf(fmaxf(m0, m1), fmaxf(m2, m3));
        float w0 = exp2f(m0 - mm), w1 = exp2f(m1 - mm);
        float w2 = exp2f(m2 - mm), w3 = exp2f(m3 - mm);
        float den = sw[0][half][e4] * w0 + sw[1][half][e4] * w1
                  + sw[2][half][e4] * w2 + sw[3][half][e4] * w3;
        float o2 = bs2f(e < 4 ? pa[2 * e]     : pb[2 * (e - 4)]);
        float o3 = bs2f(e < 4 ? pa[2 * e + 1] : pb[2 * (e - 4) + 1]);
        float num = bs2f(o0[e]) * w0 + bs2f(o1[e]) * w1 + o2 * w2 + o3 * w3;
        float xv = (e < 4) ? xa[e4] : xb[e4];
        res[e] = g * (num / den) + xv;
    }
    f32x4 ra = { res[0], res[1], res[2], res[3] };
    f32x4 rb = { res[4], res[5], res[6], res[7] };
    *(f32x4*)&out[base] = ra;
    *(f32x4*)&out[base + 4] = rb;
}

// ---------------------------------------------------------------------------
extern "C" void kernel_launch(void* const* d_in, const int* in_sizes, int n_in,
                              void* d_out, int out_size, void* d_ws, size_t ws_size,
                              hipStream_t stream) {
    const float* x  = (const float*)d_in[0];
    const float* y  = (const float*)d_in[1];
    const float* wq = (const float*)d_in[2];
    const float* wk = (const float*)d_in[3];
    const float* wv = (const float*)d_in[4];
    const float* gm = (const float*)d_in[5];
    float* out = (float*)d_out;

    char* ws = (char*)d_ws;
    const size_t SZ = (size_t)B_DIM * N_DIM * C_DIM * sizeof(short); // 8 MB
    short* xT = (short*)(ws);
    short* yT = (short*)(ws + SZ);
    short* Qb = (short*)(ws + 2 * SZ);
    short* Kb = (short*)(ws + 3 * SZ);
    short* Vb = (short*)(ws + 4 * SZ);
    short* wb = (short*)(ws + 5 * SZ); // 384 KB, dead after proj
    // overlays: Op0/Op1 -> xT/yT (dead after proj); ms -> wb region (512 KB)
    float* ms = (float*)(ws + 5 * SZ);

    prep_kernel<<<dim3(2048 + 96), dim3(256), 0, stream>>>(x, y, wq, wk, wv, xT, yT, wb);
    proj_kernel<<<dim3(3072), dim3(256), 0, stream>>>(xT, yT, wb, Qb, Kb, Vb);
    attn_kernel<<<dim3(512), dim3(256), 0, stream>>>(Qb, Kb, Vb, xT, (short*)out, ms);
    merge_kernel<<<dim3(2048), dim3(256), 0, stream>>>(xT, (const short*)out, ms, x, gm, out);
}

// Round 8
// 164.679 us; speedup vs baseline: 2.5299x; 1.0062x over previous
//
#include <hip/hip_runtime.h>
#include <hip/hip_bf16.h>
#include <stdint.h>

#define C_DIM 256
#define N_DIM 4096
#define B_DIM 4

typedef __attribute__((ext_vector_type(8))) short s16x8;   // 8 bf16
typedef __attribute__((ext_vector_type(4))) short s16x4;   // 4 bf16
typedef __attribute__((ext_vector_type(4))) float f32x4;
typedef __attribute__((ext_vector_type(16))) float f32x16;
typedef __attribute__((ext_vector_type(4))) int i32x4;

static __device__ __forceinline__ short f2bs(float f) {
    __bf16 h = (__bf16)f;                 // RNE f32->bf16
    return __builtin_bit_cast(short, h);
}
static __device__ __forceinline__ float bs2f(short s) {
    unsigned int u = ((unsigned int)(unsigned short)s) << 16;
    return __builtin_bit_cast(float, u);
}
static __device__ __forceinline__ unsigned cvtpk(float lo, float hi) {
    unsigned r;
    asm("v_cvt_pk_bf16_f32 %0, %1, %2" : "=v"(r) : "v"(lo), "v"(hi));
    return r;
}
// v_permlane32_swap_b32: a' = {a.lo32lanes, b.lo32lanes}; b' = {a.hi, b.hi}
static __device__ __forceinline__ void plswap(unsigned &a, unsigned &b) {
    asm("v_permlane32_swap_b32 %0, %1" : "+v"(a), "+v"(b));
}

// ---------------------------------------------------------------------------
// Kernel 0: transpose+convert x,y -> xT,yT [B][N][C] bf16; convert weights.
// ---------------------------------------------------------------------------
__global__ __launch_bounds__(256)
void prep_kernel(const float* __restrict__ x, const float* __restrict__ y,
                 const float* __restrict__ wq, const float* __restrict__ wk,
                 const float* __restrict__ wv,
                 short* __restrict__ xT, short* __restrict__ yT,
                 short* __restrict__ wb)
{
    int bid = blockIdx.x;
    int t = threadIdx.x;
    if (bid < 2048) {
        const float* src = (bid < 1024) ? x : y;
        short* dst = (bid < 1024) ? xT : yT;
        int id = bid & 1023;
        int ct = id & 3;            // 4 c-tiles of 64
        int nt = (id >> 2) & 63;    // 64 n-tiles of 64
        int b  = id >> 8;           // 4 batches
        int n0 = nt * 64, c0 = ct * 64;
        __shared__ short T[64][66]; // odd dword stride -> conflict-free
        int l = t & 63;
        int wv_ = t >> 6;
        #pragma unroll
        for (int p = 0; p < 16; ++p) {
            int c = wv_ + p * 4;
            float v = src[((size_t)(b * C_DIM + c0 + c)) * N_DIM + n0 + l];
            T[l][c] = f2bs(v);
        }
        __syncthreads();
        #pragma unroll
        for (int p = 0; p < 16; ++p) {
            int n = wv_ + p * 4;
            dst[((size_t)(b * N_DIM + n0 + n)) * C_DIM + c0 + l] = T[n][l];
        }
    } else {
        // weights: 96 blocks x 2048 elems
        int id = bid - 2048;
        const float* w = (id < 32) ? wq : (id < 64) ? wk : wv;
        short* dst = wb + (size_t)(id / 32) * (C_DIM * C_DIM);
        int off = (id & 31) * 2048 + t * 8;
        f32x4 a  = *(const f32x4*)(w + off);
        f32x4 b4 = *(const f32x4*)(w + off + 4);
        s16x8 r;
        r[0]=f2bs(a[0]);  r[1]=f2bs(a[1]);  r[2]=f2bs(a[2]);  r[3]=f2bs(a[3]);
        r[4]=f2bs(b4[0]); r[5]=f2bs(b4[1]); r[6]=f2bs(b4[2]); r[7]=f2bs(b4[3]);
        *(s16x8*)(dst + off) = r;
    }
}

// ---------------------------------------------------------------------------
// Kernel 1: projections. Qb,Kb = [B][N][256]; Vb = [B][256][N].
// Q is pre-scaled by log2(e) so attention softmax can use exp2 directly.
// ---------------------------------------------------------------------------
__global__ __launch_bounds__(256)
void proj_kernel(const short* __restrict__ xT, const short* __restrict__ yT,
                 const short* __restrict__ wb,
                 short* __restrict__ Qb, short* __restrict__ Kb,
                 short* __restrict__ Vb)
{
    int bid = blockIdx.x;              // 3072 = 12 * 64 * 4
    int ot = bid & 3;
    int nt = (bid >> 2) & 63;
    int bp = bid >> 8;                 // 0..11 = b*3 + p
    int b = bp / 3, p = bp % 3;
    int n0 = nt * 64, o0 = ot * 64;
    const short* src = (p == 0) ? xT : yT;
    const short* w = wb + (size_t)p * C_DIM * C_DIM;

    __shared__ __align__(16) short Xs[64][264];

    int t = threadIdx.x;
    const short* srcb = src + (size_t)(b * N_DIM + n0) * C_DIM;
    #pragma unroll
    for (int pas = 0; pas < 8; ++pas) {
        int slot = pas * 256 + t;
        int row = slot >> 5, ck = slot & 31;
        *(s16x8*)&Xs[row][ck * 8] = *(const s16x8*)&srcb[(size_t)row * C_DIM + ck * 8];
    }
    __syncthreads();

    int lane = t & 63;
    int wid = t >> 6;
    int m = lane & 15, q = lane >> 4;
    f32x4 acc[4] = {};

    if (p < 2) {
        #pragma unroll
        for (int kk = 0; kk < 8; ++kk) {
            s16x8 af = *(const s16x8*)&Xs[wid * 16 + m][kk * 32 + q * 8];
            #pragma unroll
            for (int ob = 0; ob < 4; ++ob) {
                s16x8 bf = *(const s16x8*)&w[(size_t)(o0 + ob * 16 + m) * C_DIM + kk * 32 + q * 8];
                acc[ob] = __builtin_amdgcn_mfma_f32_16x16x32_bf16(af, bf, acc[ob], 0, 0, 0);
            }
        }
        float sc = (p == 0) ? 1.4426950408889634f : 1.0f;  // log2(e) for Q
        short* dst = ((p == 0) ? Qb : Kb) + (size_t)b * N_DIM * C_DIM;
        #pragma unroll
        for (int ob = 0; ob < 4; ++ob)
            #pragma unroll
            for (int r = 0; r < 4; ++r) {
                int n = n0 + wid * 16 + q * 4 + r;
                int o = o0 + ob * 16 + m;
                dst[(size_t)n * C_DIM + o] = f2bs(acc[ob][r] * sc);
            }
    } else {
        #pragma unroll
        for (int kk = 0; kk < 8; ++kk) {
            s16x8 af = *(const s16x8*)&w[(size_t)(o0 + wid * 16 + m) * C_DIM + kk * 32 + q * 8];
            #pragma unroll
            for (int nb = 0; nb < 4; ++nb) {
                s16x8 bf = *(const s16x8*)&Xs[nb * 16 + m][kk * 32 + q * 8];
                acc[nb] = __builtin_amdgcn_mfma_f32_16x16x32_bf16(af, bf, acc[nb], 0, 0, 0);
            }
        }
        short* dst = Vb + (size_t)b * C_DIM * N_DIM;
        #pragma unroll
        for (int nb = 0; nb < 4; ++nb)
            #pragma unroll
            for (int r = 0; r < 4; ++r) {
                int o = o0 + wid * 16 + q * 4 + r;
                int n = n0 + nb * 16 + m;
                dst[(size_t)o * N_DIM + n] = f2bs(acc[nb][r]);
            }
    }
}

// ---------------------------------------------------------------------------
// Kernel 2: WAVE-INDEPENDENT flash attention, ksplit=4, STAGE-ONCE blocks.
// Grid 256 x 512thr (8 waves); each wave owns 32 q-rows END-TO-END (R7's
// verified per-wave code: swapped QK -> in-register softmax -> cvt_pk +
// permlane32_swap P-fragments -> PV over 256 channels, acc 8x f32x16).
// New shell vs R7: ONE block/CU stages each K/V tile ONCE for 8 waves
// (R7: two 4-wave blocks duplicated staging); LDS double-buffered
// (74.8 KB) so stage-writes go to buf nx while reads hit cur ->
// ONE barrier per jt instead of two.
// Partials: ks 0/1 -> Op01 (dead xT/yT); ks 2/3 -> packed bf16 pairs inside
// out's f32 slots (disjoint 2B stores). merge_kernel normalizes.
// ---------------------------------------------------------------------------
__global__ __launch_bounds__(512, 2)
void attn_kernel(const short* __restrict__ Qb, const short* __restrict__ Kb,
                 const short* __restrict__ Vb,
                 short* __restrict__ Op01, short* __restrict__ Op23,
                 float* __restrict__ ms)
{
    int bid0 = blockIdx.x;
    int swz = (bid0 & 7) * 32 + (bid0 >> 3);   // XCD swizzle: 32 blocks/XCD,
    int b  = swz >> 6;                          // contiguous (b,ks) groups
    int ks = (swz >> 4) & 3;
    int qt = swz & 15;

    int t = threadIdx.x;
    int wv = t >> 6;
    int lane = t & 63;
    int il = lane & 31, hi = lane >> 5;
    int q0 = qt * 256 + wv * 32;

    __shared__ __align__(16) short Ksh[2][32][264];   // 33.8 KB
    __shared__ __align__(16) short Vsh[2][256][40];   // 41.0 KB -> 74.8 KB total

    const short* Qp = Qb + (size_t)b * N_DIM * C_DIM;
    const short* Kp = Kb + (size_t)b * N_DIM * C_DIM + (size_t)(ks * 1024) * C_DIM;
    const short* Vp = Vb + (size_t)b * C_DIM * N_DIM + ks * 1024;

    // Q fragments: B[k=c][col=q], lane holds q = q0+il, c = kk*16+hi*8+e
    s16x8 qf[16];
    {
        const short* qrow = Qp + (size_t)(q0 + il) * C_DIM + hi * 8;
        #pragma unroll
        for (int kk = 0; kk < 16; ++kk)
            qf[kk] = *(const s16x8*)&qrow[kk * 16];
    }

    // staging maps (512 threads, 2 x 16B chunks each for K and V)
    int krow = t >> 5, kcol = (t & 31) * 8;   // K rows p*16+krow (32x256)
    int vrow = t >> 2, vcol = (t & 3) * 8;    // V rows p*128+vrow (256x32)

    // prologue: stage tile 0 into buffer 0
    {
        s16x8 kr[2], vr[2];
        #pragma unroll
        for (int p = 0; p < 2; ++p)
            kr[p] = *(const s16x8*)&Kp[(size_t)(p * 16 + krow) * C_DIM + kcol];
        #pragma unroll
        for (int p = 0; p < 2; ++p)
            vr[p] = *(const s16x8*)&Vp[(size_t)(p * 128 + vrow) * N_DIM + vcol];
        #pragma unroll
        for (int p = 0; p < 2; ++p) *(s16x8*)&Ksh[0][p * 16 + krow][kcol] = kr[p];
        #pragma unroll
        for (int p = 0; p < 2; ++p) *(s16x8*)&Vsh[0][p * 128 + vrow][vcol] = vr[p];
    }
    __syncthreads();

    f32x16 acc[8] = {};               // O^T[c = cs*32+crow(r,hi)][q = il]
    float mrun = -1e30f, srun = 0.f;
    int cur = 0;

    for (int jt = 0; jt < 32; ++jt) {
        bool pfch = (jt < 31);
        int nx = cur ^ 1;

        // issue next-tile global loads first (latency hides under QK+softmax)
        s16x8 kr[2], vr[2];
        if (pfch) {
            const short* kg = Kp + (size_t)((jt + 1) * 32) * C_DIM;
            #pragma unroll
            for (int p = 0; p < 2; ++p)
                kr[p] = *(const s16x8*)&kg[(size_t)(p * 16 + krow) * C_DIM + kcol];
            const short* vg = Vp + (jt + 1) * 32;
            #pragma unroll
            for (int p = 0; p < 2; ++p)
                vr[p] = *(const s16x8*)&vg[(size_t)(p * 128 + vrow) * N_DIM + vcol];
        }

        // ---- QK: 2 independent 8-chains --------------------------------
        f32x16 sv0 = {}, sv1 = {};
        __builtin_amdgcn_s_setprio(1);
        #pragma unroll
        for (int kk = 0; kk < 8; ++kk) {
            s16x8 a0 = *(const s16x8*)&Ksh[cur][il][kk * 16 + hi * 8];
            sv0 = __builtin_amdgcn_mfma_f32_32x32x16_bf16(a0, qf[kk], sv0, 0, 0, 0);
            s16x8 a1 = *(const s16x8*)&Ksh[cur][il][(kk + 8) * 16 + hi * 8];
            sv1 = __builtin_amdgcn_mfma_f32_32x32x16_bf16(a1, qf[kk + 8], sv1, 0, 0, 0);
        }
        __builtin_amdgcn_s_setprio(0);
        #pragma unroll
        for (int r = 0; r < 16; ++r) sv0[r] += sv1[r];

        // ---- in-register softmax (T13 defer-max, THR=8 in log2 units) ---
        float tmax = sv0[0];
        #pragma unroll
        for (int r = 1; r < 16; ++r) tmax = fmaxf(tmax, sv0[r]);
        tmax = fmaxf(tmax, __shfl_xor(tmax, 32, 64));
        if (__any(tmax > mrun + 8.f)) {
            float mnew = fmaxf(mrun, tmax);
            float alpha = exp2f(mrun - mnew);
            mrun = mnew;
            srun *= alpha;
            #pragma unroll
            for (int cs = 0; cs < 8; ++cs)
                #pragma unroll
                for (int r = 0; r < 16; ++r) acc[cs][r] *= alpha;
        }
        float ts = 0.f;
        #pragma unroll
        for (int r = 0; r < 16; ++r) {
            float pe = exp2f(sv0[r] - mrun);   // Q pre-scaled by log2(e)
            sv0[r] = pe;
            ts += pe;
        }
        ts += __shfl_xor(ts, 32, 64);
        srun += ts;

        // ---- P -> bf16 PV B-fragments (cvt_pk + permlane32_swap) --------
        unsigned d0[4], d1[4];
        #pragma unroll
        for (int rq = 0; rq < 4; ++rq) {
            d0[rq] = cvtpk(sv0[4 * rq + 0], sv0[4 * rq + 1]);
            d1[rq] = cvtpk(sv0[4 * rq + 2], sv0[4 * rq + 3]);
        }
        unsigned w0a = d0[0], w2a = d0[1]; plswap(w0a, w2a);
        unsigned w1a = d1[0], w3a = d1[1]; plswap(w1a, w3a);
        unsigned w0b = d0[2], w2b = d0[3]; plswap(w0b, w2b);
        unsigned w1b = d1[2], w3b = d1[3]; plswap(w1b, w3b);
        i32x4 pi0 = { (int)w0a, (int)w1a, (int)w2a, (int)w3a };
        i32x4 pi1 = { (int)w0b, (int)w1b, (int)w2b, (int)w3b };
        s16x8 pf0 = __builtin_bit_cast(s16x8, pi0);   // keys 0..15 of tile
        s16x8 pf1 = __builtin_bit_cast(s16x8, pi1);   // keys 16..31

        // ---- stage-write next tile into buffer nx (no reader this jt) ---
        if (pfch) {
            #pragma unroll
            for (int p = 0; p < 2; ++p) *(s16x8*)&Ksh[nx][p * 16 + krow][kcol] = kr[p];
            #pragma unroll
            for (int p = 0; p < 2; ++p) *(s16x8*)&Vsh[nx][p * 128 + vrow][vcol] = vr[p];
        }

        // ---- PV: 8 c-strips x 2 k-slices, 8 independent acc chains ------
        __builtin_amdgcn_s_setprio(1);
        #pragma unroll
        for (int cs = 0; cs < 8; ++cs) {
            s16x8 va = *(const s16x8*)&Vsh[cur][cs * 32 + il][hi * 8];
            acc[cs] = __builtin_amdgcn_mfma_f32_32x32x16_bf16(va, pf0, acc[cs], 0, 0, 0);
            s16x8 vb = *(const s16x8*)&Vsh[cur][cs * 32 + il][16 + hi * 8];
            acc[cs] = __builtin_amdgcn_mfma_f32_32x32x16_bf16(vb, pf1, acc[cs], 0, 0, 0);
        }
        __builtin_amdgcn_s_setprio(0);

        __syncthreads();   // single barrier: cur reads done + nx writes done
        cur = nx;
    }

    // ---- epilogue: unnormalized O^T partial (bf16) + per-q (m, s) -------
    int i = q0 + il;
    const size_t HSZ = (size_t)B_DIM * C_DIM * N_DIM;
    if (ks < 2) {
        short* o = Op01 + (size_t)ks * HSZ + (size_t)(b * C_DIM) * N_DIM + i;
        #pragma unroll
        for (int cs = 0; cs < 8; ++cs)
            #pragma unroll
            for (int r = 0; r < 16; ++r) {
                int c = cs * 32 + (r & 3) + 8 * (r >> 2) + 4 * hi;
                o[(size_t)c * N_DIM] = f2bs(acc[cs][r]);
            }
    } else {
        // pack as bf16 pair inside out's f32 slot: [2*idx + (ks-2)]
        short* o = Op23 + ((size_t)(b * C_DIM) * N_DIM + i) * 2 + (ks - 2);
        #pragma unroll
        for (int cs = 0; cs < 8; ++cs)
            #pragma unroll
            for (int r = 0; r < 16; ++r) {
                int c = cs * 32 + (r & 3) + 8 * (r >> 2) + 4 * hi;
                o[(size_t)c * N_DIM * 2] = f2bs(acc[cs][r]);
            }
    }
    if (hi == 0) {
        float* msp = ms + ((size_t)(ks * B_DIM + b) * 2) * N_DIM;
        msp[i] = mrun;
        msp[N_DIM + i] = srun;
    }
}

// ---------------------------------------------------------------------------
// Kernel 3: 4-way flash-merge + gamma/residual epilogue.
// out = g * (sum_h O_h w_h) / (sum_h s_h w_h) + x,  w_h = 2^(m_h - max)
// Op2/3 are read from out's own f32 slots (interleaved bf16) and then the
// slot is overwritten by the SAME thread -> race-free.
// ---------------------------------------------------------------------------
__global__ __launch_bounds__(256)
void merge_kernel(const short* __restrict__ Op01, const short* Op23,
                  const float* __restrict__ ms, const float* __restrict__ x,
                  const float* __restrict__ gamma, float* out)
{
    size_t base = ((size_t)blockIdx.x * 256 + threadIdx.x) * 8;
    int n = (int)(base & (N_DIM - 1));
    int b = (int)(base >> 20);                     // 256*4096 = 2^20 per batch
    const size_t HSZ = (size_t)B_DIM * C_DIM * N_DIM;

    s16x8 o0 = *(const s16x8*)&Op01[base];
    s16x8 o1 = *(const s16x8*)&Op01[HSZ + base];
    s16x8 pa = *(const s16x8*)&Op23[base * 2];      // n..n+3 (o2,o3 pairs)
    s16x8 pb = *(const s16x8*)&Op23[base * 2 + 8];  // n+4..n+7

    f32x4 mv[4][2], sw[4][2];
    #pragma unroll
    for (int h = 0; h < 4; ++h) {
        const float* msp = ms + ((size_t)(h * B_DIM + b) * 2) * N_DIM + n;
        mv[h][0] = *(const f32x4*)&msp[0];
        mv[h][1] = *(const f32x4*)&msp[4];
        sw[h][0] = *(const f32x4*)&msp[N_DIM];
        sw[h][1] = *(const f32x4*)&msp[N_DIM + 4];
    }
    f32x4 xa = *(const f32x4*)&x[base];
    f32x4 xb = *(const f32x4*)&x[base + 4];
    float g = gamma[0];

    float res[8];
    #pragma unroll
    for (int e = 0; e < 8; ++e) {
        int half = e >> 2, e4 = e & 3;
        float m0 = mv[0][half][e4], m1 = mv[1][half][e4];
        float m2 = mv[2][half][e4], m3 = mv[3][half][e4];
        float mm = fmaxf(fmaxf(m0, m1), fmaxf(m2, m3));
        float w0 = exp2f(m0 - mm), w1 = exp2f(m1 - mm);
        float w2 = exp2f(m2 - mm), w3 = exp2f(m3 - mm);
        float den = sw[0][half][e4] * w0 + sw[1][half][e4] * w1
                  + sw[2][half][e4] * w2 + sw[3][half][e4] * w3;
        float o2 = bs2f(e < 4 ? pa[2 * e]     : pb[2 * (e - 4)]);
        float o3 = bs2f(e < 4 ? pa[2 * e + 1] : pb[2 * (e - 4) + 1]);
        float num = bs2f(o0[e]) * w0 + bs2f(o1[e]) * w1 + o2 * w2 + o3 * w3;
        float xv = (e < 4) ? xa[e4] : xb[e4];
        res[e] = g * (num / den) + xv;
    }
    f32x4 ra = { res[0], res[1], res[2], res[3] };
    f32x4 rb = { res[4], res[5], res[6], res[7] };
    *(f32x4*)&out[base] = ra;
    *(f32x4*)&out[base + 4] = rb;
}

// ---------------------------------------------------------------------------
extern "C" void kernel_launch(void* const* d_in, const int* in_sizes, int n_in,
                              void* d_out, int out_size, void* d_ws, size_t ws_size,
                              hipStream_t stream) {
    const float* x  = (const float*)d_in[0];
    const float* y  = (const float*)d_in[1];
    const float* wq = (const float*)d_in[2];
    const float* wk = (const float*)d_in[3];
    const float* wv = (const float*)d_in[4];
    const float* gm = (const float*)d_in[5];
    float* out = (float*)d_out;

    char* ws = (char*)d_ws;
    const size_t SZ = (size_t)B_DIM * N_DIM * C_DIM * sizeof(short); // 8 MB
    short* xT = (short*)(ws);
    short* yT = (short*)(ws + SZ);
    short* Qb = (short*)(ws + 2 * SZ);
    short* Kb = (short*)(ws + 3 * SZ);
    short* Vb = (short*)(ws + 4 * SZ);
    short* wb = (short*)(ws + 5 * SZ); // 384 KB, dead after proj
    // overlays: Op0/Op1 -> xT/yT (dead after proj); ms -> wb region (512 KB)
    float* ms = (float*)(ws + 5 * SZ);

    prep_kernel<<<dim3(2048 + 96), dim3(256), 0, stream>>>(x, y, wq, wk, wv, xT, yT, wb);
    proj_kernel<<<dim3(3072), dim3(256), 0, stream>>>(xT, yT, wb, Qb, Kb, Vb);
    attn_kernel<<<dim3(256), dim3(512), 0, stream>>>(Qb, Kb, Vb, xT, (short*)out, ms);
    merge_kernel<<<dim3(2048), dim3(256), 0, stream>>>(xT, (const short*)out, ms, x, gm, out);
}